// Round 9
// baseline (1087.846 us; speedup 1.0000x reference)
//
#include <hip/hip_runtime.h>
#include <hip/hip_bf16.h>

#define NNODE 50000
#define NEDGE 500000
#define SZ    4096
#define NBKT  256   // dst-range buckets per relation
#define BWID  196   // dst nodes per bucket: 256*196 = 50176 >= NNODE
#define BCAP  4096  // fixed bucket capacity (expected load 1953 +- 44; 48 sigma)
#define RELEB ((size_t)NBKT * BCAP)
#define ZK1   8     // MLP1 split-K factor (65 k-steps -> 9 per z)

typedef __attribute__((ext_vector_type(8))) short bf16x8;
typedef __attribute__((ext_vector_type(4))) float f32x4;

__device__ __forceinline__ float bits2f(unsigned short u) {
    return __uint_as_float(((unsigned)u) << 16);
}
__device__ __forceinline__ unsigned short f2bits(float f) {  // RNE fp32->bf16
    unsigned x = __float_as_uint(f);
    unsigned r = x + 0x7fffu + ((x >> 16) & 1u);
    return (unsigned short)(r >> 16);
}
__device__ __forceinline__ unsigned pk_max_u16(unsigned a, unsigned b) {
    unsigned lo = max(a & 0xffffu, b & 0xffffu);
    unsigned hi = max(a >> 16, b >> 16);
    return lo | (hi << 16);
}
// async global->LDS, 16B per lane; LDS dest = uniform base + lane*16
__device__ __forceinline__ void gl_lds16(const void* g, void* l) {
    __builtin_amdgcn_global_load_lds(
        (const __attribute__((address_space(1))) unsigned int*)g,
        (__attribute__((address_space(3))) unsigned int*)l, 16, 0, 0);
}

// ---------------------------------------------------------------------------
// Big-GEMM: 128x128 tile, BK=64, 4 waves, linear LDS, global_load_lds w16,
// XCD swizzle. PIPE=1: 2-deep LDS double-buffer (issue next tile before
// computing current) -- use when grid-starved (<~2 blocks/CU); PIPE=0:
// single-buffer 32KB (keeps 4 blocks/CU) -- use when grid fills the GPU.
// PART=1: split-K over gridDim.z, f32 partials to Cv + z*M*N (no bias/act).
// ---------------------------------------------------------------------------
template<int RELU, int SIG, int OUTF32, int PART, int PIPE>
__global__ __launch_bounds__(256)
void gemm128(const unsigned short* __restrict__ A, const unsigned short* __restrict__ Bt,
             const float* __restrict__ bias, void* __restrict__ Cv, int M, int N, int K)
{
    __shared__ unsigned short As[PIPE + 1][128 * 64];
    __shared__ unsigned short Bs[PIPE + 1][128 * 64];
    const int tid = threadIdx.x;
    const int wave = tid >> 6, lane = tid & 63;
    const int m16 = lane & 15, quad = lane >> 4;
    const int wr = wave >> 1, wc = wave & 1;
    // XCD-aware swizzle (bijective: all grids here have nwg % 8 == 0)
    const int nwg = gridDim.x * gridDim.y;
    int bid = blockIdx.y * gridDim.x + blockIdx.x;
    if ((nwg & 7) == 0) { int cpx = nwg >> 3; bid = (bid & 7) * cpx + (bid >> 3); }
    const int bx = bid % gridDim.x, by = bid / gridDim.x;
    const int row0 = by * 128, col0 = bx * 128;
    const int lrow = lane >> 3, lcol = (lane & 7) * 8;

    f32x4 acc[4][4] = {};

    int k0beg = 0, k0end = K;
    if (PART) {
        const int per = ((K >> 6) + gridDim.z - 1) / gridDim.z;
        k0beg = blockIdx.z * per * 64;
        k0end = min(K, k0beg + per * 64);
    }
    const int nt = (k0end - k0beg) >> 6;

    auto STAGE = [&](int b, int k0) {
#pragma unroll
        for (int i = 0; i < 4; ++i) {
            int chunk = wave * 4 + i;           // 16 chunks of 8 rows x 64 elems
            int row = chunk * 8 + lrow;
            gl_lds16(A  + (size_t)(row0 + row) * K + k0 + lcol, &As[b][chunk * 512]);
            gl_lds16(Bt + (size_t)(col0 + row) * K + k0 + lcol, &Bs[b][chunk * 512]);
        }
    };
    auto COMPUTE = [&](int b) {
#pragma unroll
        for (int ks = 0; ks < 2; ++ks) {
            bf16x8 a[4], bb[4];
#pragma unroll
            for (int mt = 0; mt < 4; ++mt)
                a[mt] = *(const bf16x8*)&As[b][(wr * 64 + mt * 16 + m16) * 64 + ks * 32 + quad * 8];
#pragma unroll
            for (int nt2 = 0; nt2 < 4; ++nt2)
                bb[nt2] = *(const bf16x8*)&Bs[b][(wc * 64 + nt2 * 16 + m16) * 64 + ks * 32 + quad * 8];
#pragma unroll
            for (int mt = 0; mt < 4; ++mt)
#pragma unroll
                for (int nt2 = 0; nt2 < 4; ++nt2)
                    acc[mt][nt2] = __builtin_amdgcn_mfma_f32_16x16x32_bf16(a[mt], bb[nt2], acc[mt][nt2], 0, 0, 0);
        }
    };

    if (PIPE) {
        STAGE(0, k0beg);
        __syncthreads();                        // drain prologue loads
        int cur = 0;
        for (int t = 0; t < nt; ++t) {
            if (t + 1 < nt) STAGE(cur ^ 1, k0beg + (t + 1) * 64);  // issue-early
            COMPUTE(cur);
            __syncthreads();                    // next tile arrived + cur free
            cur ^= 1;
        }
    } else {
        for (int t = 0; t < nt; ++t) {
            STAGE(0, k0beg + t * 64);
            __syncthreads();
            COMPUTE(0);
            __syncthreads();
        }
    }

    if (PART) {
        float* P = (float*)Cv + (size_t)blockIdx.z * M * N;
#pragma unroll
        for (int mt = 0; mt < 4; ++mt)
#pragma unroll
            for (int nt2 = 0; nt2 < 4; ++nt2) {
                int gc = col0 + wc * 64 + nt2 * 16 + m16;
#pragma unroll
                for (int r = 0; r < 4; ++r) {
                    int gm = row0 + wr * 64 + mt * 16 + quad * 4 + r;
                    P[(size_t)gm * N + gc] = acc[mt][nt2][r];
                }
            }
        return;
    }

#pragma unroll
    for (int mt = 0; mt < 4; ++mt) {
#pragma unroll
        for (int nt2 = 0; nt2 < 4; ++nt2) {
            int gc = col0 + wc * 64 + nt2 * 16 + m16;
            float bv = bias[gc];
#pragma unroll
            for (int r = 0; r < 4; ++r) {
                int gm = row0 + wr * 64 + mt * 16 + quad * 4 + r;
                size_t idx = (size_t)gm * N + gc;
                float v = acc[mt][nt2][r] + bv;
                if (RELU) v = fmaxf(v, 0.f);
                if (SIG)  v = 1.f / (1.f + __expf(-v));
                if (OUTF32) ((float*)Cv)[idx] = v;
                else        ((unsigned short*)Cv)[idx] = f2bits(v);
            }
        }
    }
}

// split-K reduce + bias + relu + bf16 cvt for MLP layer 1 (ZK1 partials)
__global__ __launch_bounds__(256)
void mlp1_ep_k(const float* __restrict__ p, const float* __restrict__ b1,
               unsigned short* __restrict__ x1)
{
    const size_t MN = (size_t)SZ * 256;
    int i = blockIdx.x * 256 + threadIdx.x;            // float4 groups
    if (i >= (int)(MN / 4)) return;
    float4 s = ((const float4*)p)[i];
#pragma unroll
    for (int z = 1; z < ZK1; ++z) {
        float4 a = ((const float4*)(p + (size_t)z * MN))[i];
        s.x += a.x; s.y += a.y; s.z += a.z; s.w += a.w;
    }
    int base = i * 4;
    ushort4 o;
    o.x = f2bits(fmaxf(s.x + b1[(base + 0) & 255], 0.f));
    o.y = f2bits(fmaxf(s.y + b1[(base + 1) & 255], 0.f));
    o.z = f2bits(fmaxf(s.z + b1[(base + 2) & 255], 0.f));
    o.w = f2bits(fmaxf(s.w + b1[(base + 3) & 255], 0.f));
    ((ushort4*)x1)[i] = o;
}

// ---------------------------------------------------------------------------
// Paired pool GEMM (layer 1): z = 0/1 selects (A, Bt, bias); out slot z*M*N.
// ---------------------------------------------------------------------------
template<int NT>
__global__ __launch_bounds__(256)
void pool2_k(const unsigned short* __restrict__ A0, const unsigned short* __restrict__ A1,
             const unsigned short* __restrict__ Bt0, const unsigned short* __restrict__ Bt1,
             const float* __restrict__ b0, const float* __restrict__ b1,
             unsigned short* __restrict__ out, int M, int K)
{
    __shared__ unsigned short As[64][72];
    __shared__ unsigned short Bs[NT * 16][72];
    const int z = blockIdx.z;
    const unsigned short* A = z ? A1 : A0;
    const unsigned short* Bt = z ? Bt1 : Bt0;
    const float* bias = z ? b1 : b0;
    const int N = NT * 16;
    unsigned short* Cv = out + (size_t)z * M * N;

    const int tid = threadIdx.x;
    const int wave = tid >> 6, lane = tid & 63;
    const int m16 = lane & 15, quad = lane >> 4;
    const int row0 = blockIdx.y * 64, col0 = blockIdx.x * N;

    f32x4 acc[NT] = {};

    for (int k0 = 0; k0 < K; k0 += 64) {
#pragma unroll
        for (int it = 0; it < 2; ++it) {
            int u = tid + it * 256;
            int m = u >> 3, c = (u & 7) * 8;
            int gm = row0 + m;
            uint4 v = make_uint4(0u, 0u, 0u, 0u);
            if (gm < M) v = *(const uint4*)(A + (size_t)gm * K + k0 + c);
            *(uint4*)&As[m][c] = v;
        }
#pragma unroll
        for (int it = 0; it < NT / 2; ++it) {
            int u = tid + it * 256;
            int n = u >> 3, c = (u & 7) * 8;
            uint4 v = *(const uint4*)(Bt + (size_t)(col0 + n) * K + k0 + c);
            *(uint4*)&Bs[n][c] = v;
        }
        __syncthreads();
#pragma unroll
        for (int ks = 0; ks < 2; ++ks) {
            bf16x8 a = *(const bf16x8*)&As[wave * 16 + m16][ks * 32 + quad * 8];
#pragma unroll
            for (int nt = 0; nt < NT; ++nt) {
                bf16x8 b = *(const bf16x8*)&Bs[nt * 16 + m16][ks * 32 + quad * 8];
                acc[nt] = __builtin_amdgcn_mfma_f32_16x16x32_bf16(a, b, acc[nt], 0, 0, 0);
            }
        }
        __syncthreads();
    }

#pragma unroll
    for (int nt = 0; nt < NT; ++nt) {
        int gc = col0 + nt * 16 + m16;
        float bv = bias[gc];
#pragma unroll
        for (int r = 0; r < 4; ++r) {
            int gm = row0 + wave * 16 + quad * 4 + r;
            if (gm < M)
                Cv[(size_t)gm * N + gc] = f2bits(fmaxf(acc[nt][r] + bv, 0.f));
        }
    }
}

// ---------------------------------------------------------------------------
// All-relation pool GEMM (layers 2/3): z = relation 0..5.
// ---------------------------------------------------------------------------
__global__ __launch_bounds__(256)
void pool6_k(const unsigned short* __restrict__ hin, const unsigned short* __restrict__ pT,
             const float* __restrict__ bp, unsigned short* __restrict__ pooled6, int M)
{
    const int SRCr[6] = {0, 1, 0, 2, 2, 1};
    __shared__ unsigned short As[64][72];
    __shared__ unsigned short Bs[64][72];
    const int z = blockIdx.z;
    const unsigned short* A = hin + (size_t)SRCr[z] * M * 64;
    const unsigned short* Bt = pT + (size_t)z * 4096;
    const float* bias = bp + z * 64;
    unsigned short* Cv = pooled6 + (size_t)z * M * 64;

    const int tid = threadIdx.x;
    const int wave = tid >> 6, lane = tid & 63;
    const int m16 = lane & 15, quad = lane >> 4;
    const int row0 = blockIdx.y * 64;

    f32x4 acc[4] = {};

    {
#pragma unroll
        for (int it = 0; it < 2; ++it) {
            int u = tid + it * 256;
            int m = u >> 3, c = (u & 7) * 8;
            int gm = row0 + m;
            uint4 v = make_uint4(0u, 0u, 0u, 0u);
            if (gm < M) v = *(const uint4*)(A + (size_t)gm * 64 + c);
            *(uint4*)&As[m][c] = v;
        }
#pragma unroll
        for (int it = 0; it < 2; ++it) {
            int u = tid + it * 256;
            int n = u >> 3, c = (u & 7) * 8;
            uint4 v = *(const uint4*)(Bt + (size_t)n * 64 + c);
            *(uint4*)&Bs[n][c] = v;
        }
        __syncthreads();
#pragma unroll
        for (int ks = 0; ks < 2; ++ks) {
            bf16x8 a = *(const bf16x8*)&As[wave * 16 + m16][ks * 32 + quad * 8];
#pragma unroll
            for (int nt = 0; nt < 4; ++nt) {
                bf16x8 b = *(const bf16x8*)&Bs[nt * 16 + m16][ks * 32 + quad * 8];
                acc[nt] = __builtin_amdgcn_mfma_f32_16x16x32_bf16(a, b, acc[nt], 0, 0, 0);
            }
        }
    }

#pragma unroll
    for (int nt = 0; nt < 4; ++nt) {
        int gc = nt * 16 + m16;
        float bv = bias[gc];
#pragma unroll
        for (int r = 0; r < 4; ++r) {
            int gm = row0 + wave * 16 + quad * 4 + r;
            if (gm < M)
                Cv[(size_t)gm * 64 + gc] = f2bits(fmaxf(acc[nt][r] + bv, 0.f));
        }
    }
}

// ---------------------------------------------------------------------------
// Fused dst-pair GEMM (layer 1 pair version).
// ---------------------------------------------------------------------------
template<int NT>
__global__ __launch_bounds__(256)
void mfma_gemm(const unsigned short* __restrict__ A1, const unsigned short* __restrict__ A2,
               const unsigned short* __restrict__ A3,
               const unsigned short* __restrict__ Bt, const float* __restrict__ bias,
               const float* __restrict__ bias2,
               unsigned short* __restrict__ Cv, int M, int N, int Ka, int Kb, int Kc)
{
    __shared__ unsigned short As[64][72];
    __shared__ unsigned short Bs[NT * 16][72];
    const int tid = threadIdx.x;
    const int wave = tid >> 6, lane = tid & 63;
    const int m16 = lane & 15, quad = lane >> 4;
    const int row0 = blockIdx.y * 64, col0 = blockIdx.x * (NT * 16);
    const int K = Ka + Kb + Kc;

    f32x4 acc[NT] = {};

    for (int k0 = 0; k0 < K; k0 += 64) {
        const int seg = (k0 >= Ka + Kb) ? 2 : ((k0 >= Ka) ? 1 : 0);
        const unsigned short* src = seg == 2 ? A3 : (seg == 1 ? A2 : A1);
        const int ld = seg == 2 ? Kc : (seg == 1 ? Kb : Ka);
        const int kb = k0 - (seg == 2 ? Ka + Kb : (seg == 1 ? Ka : 0));
#pragma unroll
        for (int it = 0; it < 2; ++it) {
            int u = tid + it * 256;
            int m = u >> 3, c = (u & 7) * 8;
            int gm = row0 + m;
            uint4 v = make_uint4(0u, 0u, 0u, 0u);
            if (gm < M) v = *(const uint4*)(src + (size_t)gm * ld + kb + c);
            *(uint4*)&As[m][c] = v;
        }
#pragma unroll
        for (int it = 0; it < NT / 2; ++it) {
            int u = tid + it * 256;
            int n = u >> 3, c = (u & 7) * 8;
            uint4 v = *(const uint4*)(Bt + (size_t)(col0 + n) * K + k0 + c);
            *(uint4*)&Bs[n][c] = v;
        }
        __syncthreads();
#pragma unroll
        for (int ks = 0; ks < 2; ++ks) {
            bf16x8 a = *(const bf16x8*)&As[wave * 16 + m16][ks * 32 + quad * 8];
#pragma unroll
            for (int nt = 0; nt < NT; ++nt) {
                bf16x8 b = *(const bf16x8*)&Bs[nt * 16 + m16][ks * 32 + quad * 8];
                acc[nt] = __builtin_amdgcn_mfma_f32_16x16x32_bf16(a, b, acc[nt], 0, 0, 0);
            }
        }
        __syncthreads();
    }

#pragma unroll
    for (int nt = 0; nt < NT; ++nt) {
        int gc = col0 + nt * 16 + m16;
        float bv = bias[gc] + bias2[gc];
#pragma unroll
        for (int r = 0; r < 4; ++r) {
            int gm = row0 + wave * 16 + quad * 4 + r;
            if (gm < M)
                Cv[(size_t)gm * N + gc] = f2bits(acc[nt][r] + bv);
        }
    }
}

// ---------------------------------------------------------------------------
// All-pairs fused GEMM (layers 2/3): z = dst pair 0..2, K = 192.
// ---------------------------------------------------------------------------
__global__ __launch_bounds__(256)
void fused3_k(const unsigned short* __restrict__ hin,
              const unsigned short* __restrict__ regA, const unsigned short* __restrict__ regB,
              const unsigned short* __restrict__ fT, const float* __restrict__ bs,
              unsigned short* __restrict__ hout, int M)
{
    const int PAe[3] = {1, 0, 2}, PBe[3] = {3, 4, 5};
    __shared__ unsigned short As[64][72];
    __shared__ unsigned short Bs[64][72];
    const int z = blockIdx.z;
    const int eA = PAe[z], eB = PBe[z];
    const unsigned short* A1 = hin + (size_t)z * M * 64;
    const unsigned short* A2 = (eA < 4) ? regA + (size_t)eA * M * 64 : regB + (size_t)(eA - 4) * M * 64;
    const unsigned short* A3 = (eB < 4) ? regA + (size_t)eB * M * 64 : regB + (size_t)(eB - 4) * M * 64;
    const unsigned short* Bt = fT + (size_t)z * 12288;
    const float* bias = bs + eA * 64;
    const float* bias2 = bs + eB * 64;
    unsigned short* Cv = hout + (size_t)z * M * 64;

    const int tid = threadIdx.x;
    const int wave = tid >> 6, lane = tid & 63;
    const int m16 = lane & 15, quad = lane >> 4;
    const int row0 = blockIdx.y * 64;

    f32x4 acc[4] = {};

#pragma unroll
    for (int seg = 0; seg < 3; ++seg) {
        const unsigned short* src = seg == 2 ? A3 : (seg == 1 ? A2 : A1);
        const int k0 = seg * 64;
#pragma unroll
        for (int it = 0; it < 2; ++it) {
            int u = tid + it * 256;
            int m = u >> 3, c = (u & 7) * 8;
            int gm = row0 + m;
            uint4 v = make_uint4(0u, 0u, 0u, 0u);
            if (gm < M) v = *(const uint4*)(src + (size_t)gm * 64 + c);
            *(uint4*)&As[m][c] = v;
        }
#pragma unroll
        for (int it = 0; it < 2; ++it) {
            int u = tid + it * 256;
            int n = u >> 3, c = (u & 7) * 8;
            uint4 v = *(const uint4*)(Bt + (size_t)n * 192 + k0 + c);
            *(uint4*)&Bs[n][c] = v;
        }
        __syncthreads();
#pragma unroll
        for (int ks = 0; ks < 2; ++ks) {
            bf16x8 a = *(const bf16x8*)&As[wave * 16 + m16][ks * 32 + quad * 8];
#pragma unroll
            for (int nt = 0; nt < 4; ++nt) {
                bf16x8 b = *(const bf16x8*)&Bs[nt * 16 + m16][ks * 32 + quad * 8];
                acc[nt] = __builtin_amdgcn_mfma_f32_16x16x32_bf16(a, b, acc[nt], 0, 0, 0);
            }
        }
        __syncthreads();
    }

#pragma unroll
    for (int nt = 0; nt < 4; ++nt) {
        int gc = nt * 16 + m16;
        float bv = bias[gc] + bias2[gc];
#pragma unroll
        for (int r = 0; r < 4; ++r) {
            int gm = row0 + wave * 16 + quad * 4 + r;
            if (gm < M)
                Cv[(size_t)gm * 64 + gc] = f2bits(acc[nt][r] + bv);
        }
    }
}

// ---------------------------------------------------------------------------
__global__ __launch_bounds__(256)
void transpose_cvt(const float* __restrict__ src1, const float* __restrict__ src2,
                   unsigned short* __restrict__ dst, int R1, int R2, int Nn)
{
    __shared__ float tile[32][33];
    const int R = R1 + R2;
    const int e = blockIdx.z;
    src1 += (size_t)e * R1 * Nn;
    if (src2) src2 += (size_t)e * R2 * Nn;
    dst += (size_t)e * Nn * R;
    const int r0 = blockIdx.x * 32, n0 = blockIdx.y * 32;
    const int lr = threadIdx.x >> 5, ln = threadIdx.x & 31;
#pragma unroll
    for (int i = 0; i < 4; ++i) {
        int r = r0 + lr + i * 8, n = n0 + ln;
        float v = 0.f;
        if (r < R && n < Nn) v = (r < R1) ? src1[(size_t)r * Nn + n]
                                          : src2[(size_t)(r - R1) * Nn + n];
        tile[lr + i * 8][ln] = v;
    }
    __syncthreads();
#pragma unroll
    for (int i = 0; i < 4; ++i) {
        int n = n0 + lr + i * 8, r = r0 + ln;
        if (n < Nn && r < R) dst[(size_t)n * R + r] = f2bits(tile[ln][lr + i * 8]);
    }
}

// fused self+neigh weight prep for dst pair p: Bt[p] = [T(Ws[eA]+Ws[eB]) |
// T(Wn[eA]) | T(Wn[eB])] as [64][3F] bf16.  pairs by dst: (1,3),(0,4),(2,5)
__global__ __launch_bounds__(256)
void fuse_w_k(const float* __restrict__ Ws, const float* __restrict__ Wn,
              unsigned short* __restrict__ dst, int F)
{
    const int PAe[3] = {1, 0, 2}, PBe[3] = {3, 4, 5};
    __shared__ float tile[32][33];
    const int p = blockIdx.z;
    const int eA = PAe[p], eB = PBe[p];
    const int Kt = 3 * F;
    unsigned short* D = dst + (size_t)p * 64 * Kt;
    const int r0 = blockIdx.x * 32;       // over F
    const int n0 = blockIdx.y * 32;       // over 64 out-cols
    const int lr = threadIdx.x >> 5, ln = threadIdx.x & 31;
    for (int seg = 0; seg < 3; ++seg) {
        __syncthreads();
#pragma unroll
        for (int i = 0; i < 4; ++i) {
            int r = r0 + lr + i * 8, n = n0 + ln;
            float v;
            if (seg == 0)
                v = Ws[((size_t)eA * F + r) * 64 + n] + Ws[((size_t)eB * F + r) * 64 + n];
            else if (seg == 1)
                v = Wn[((size_t)eA * F + r) * 64 + n];
            else
                v = Wn[((size_t)eB * F + r) * 64 + n];
            tile[lr + i * 8][ln] = v;
        }
        __syncthreads();
        const int koff = seg * F;
#pragma unroll
        for (int i = 0; i < 4; ++i) {
            int n = n0 + lr + i * 8, r = r0 + ln;
            D[(size_t)n * Kt + koff + r] = f2bits(tile[ln][lr + i * 8]);
        }
    }
}

// 3 h0 feature matrices -> bf16, batched over z
__global__ __launch_bounds__(256)
void cvt3_k(const float* __restrict__ s0, const float* __restrict__ s1,
            const float* __restrict__ s2, unsigned short* __restrict__ dst)
{
    const int z = blockIdx.z;
    const float* src = z == 0 ? s0 : (z == 1 ? s1 : s2);
    dst += (size_t)z * NNODE * 128;
    int i = blockIdx.x * 256 + threadIdx.x;
    if (i >= 1600000) return;
    float4 v = ((const float4*)src)[i];
    ushort4 w;
    w.x = f2bits(v.x); w.y = f2bits(v.y); w.z = f2bits(v.z); w.w = f2bits(v.w);
    ((ushort4*)dst)[i] = w;
}

// Adj fp32 [4096][4096] -> bf16 strided [4096][4160] (fake tail filled later)
__global__ __launch_bounds__(256)
void cvt_adj_k(const float* __restrict__ src, unsigned short* __restrict__ dst)
{
    int i = blockIdx.x * 256 + threadIdx.x;           // 4,194,304 float4 groups
    if (i >= 4194304) return;
    int r = i >> 10, c4 = i & 1023;
    float4 v = ((const float4*)src)[i];
    ushort4 w;
    w.x = f2bits(v.x); w.y = f2bits(v.y); w.z = f2bits(v.z); w.w = f2bits(v.w);
    *(ushort4*)(dst + (size_t)r * 4160 + c4 * 4) = w;
}

// ---------------------------------------------------------------------------
// CSR build, atomic-histogram-free.
// ---------------------------------------------------------------------------
__global__ __launch_bounds__(256)
void binit_k(int* __restrict__ bcur)
{
    bcur[blockIdx.x * NBKT + threadIdx.x] = threadIdx.x * BCAP;
}

__global__ __launch_bounds__(256)
void bucket_k(const int* __restrict__ edges, int* __restrict__ bcur,
              unsigned* __restrict__ ebuf)
{
    const int r = blockIdx.y;
    const int base = blockIdx.x * 4096;
    const int tid = threadIdx.x;
    __shared__ int lcnt[NBKT];
    __shared__ int lbase[NBKT];
    for (int i = tid; i < NBKT; i += 256) lcnt[i] = 0;
    __syncthreads();
    unsigned ent[16];
    int rnk[16];
#pragma unroll
    for (int i = 0; i < 16; ++i) {
        int e = base + tid + i * 256;
        ent[i] = 0xffffffffu;
        rnk[i] = 0;
        if (e < NEDGE) {
            int src = edges[(size_t)r * 2 * NEDGE + e];
            int dst = edges[(size_t)r * 2 * NEDGE + NEDGE + e];
            ent[i] = ((unsigned)dst << 16) | (unsigned)src;
            rnk[i] = atomicAdd(&lcnt[dst / BWID], 1);
        }
    }
    __syncthreads();
    for (int i = tid; i < NBKT; i += 256)
        lbase[i] = lcnt[i] ? atomicAdd(&bcur[r * NBKT + i], lcnt[i]) : 0;
    __syncthreads();
#pragma unroll
    for (int i = 0; i < 16; ++i)
        if (ent[i] != 0xffffffffu) {
            int b = (int)(ent[i] >> 16) / BWID;
            int pos = lbase[b] + rnk[i];
            if (pos < (b + 1) * BCAP)   // statistically unreachable overflow guard
                ebuf[(size_t)r * RELEB + pos] = ent[i];
        }
}

__global__ __launch_bounds__(256)
void bscan_k(const int* __restrict__ bcur, int* __restrict__ bbase,
             int* __restrict__ offs)
{
    const int r = blockIdx.x, tid = threadIdx.x;
    const int lane = tid & 63, wv = tid >> 6;
    int v = bcur[r * NBKT + tid] - tid * BCAP;
    if (v > BCAP) v = BCAP;
    int x = v;
#pragma unroll
    for (int off = 1; off < 64; off <<= 1) {
        int t = __shfl_up(x, off);
        if (lane >= off) x += t;
    }
    __shared__ int wsum[4];
    if (lane == 63) wsum[wv] = x;
    __syncthreads();
    int add = 0;
#pragma unroll
    for (int w = 0; w < 4; ++w) if (w < wv) add += wsum[w];
    x += add;
    bbase[r * NBKT + tid] = x - v;
    if (tid == 255) offs[(size_t)r * (NNODE + 1) + NNODE] = x;
}

__global__ __launch_bounds__(256)
void debucket_k(const unsigned* __restrict__ ebuf, const int* __restrict__ bcur,
                const int* __restrict__ bbase, int* __restrict__ offs,
                unsigned short* __restrict__ srcs)
{
    const int r = blockIdx.y, b = blockIdx.x, tid = threadIdx.x;
    const int lo = b * BWID;
    __shared__ unsigned es[BCAP];
    __shared__ unsigned short stage[BCAP];
    __shared__ int lhist[256];
    __shared__ int buf[256];
    __shared__ int lcur[256];
    int cnt = bcur[r * NBKT + b] - b * BCAP;
    if (cnt > BCAP) cnt = BCAP;
    const int base = bbase[r * NBKT + b];
    lhist[tid] = 0;
    __syncthreads();
    for (int j = tid; j < cnt; j += 256) {
        unsigned e = ebuf[(size_t)r * RELEB + (size_t)b * BCAP + j];
        es[j] = e;
        atomicAdd(&lhist[(int)(e >> 16) - lo], 1);
    }
    __syncthreads();
    int v = lhist[tid];
    buf[tid] = v;
    __syncthreads();
    for (int off = 1; off < 256; off <<= 1) {
        int t = (tid >= off) ? buf[tid - off] : 0;
        __syncthreads();
        buf[tid] += t;
        __syncthreads();
    }
    int excl = buf[tid] - v;
    int node = lo + tid;
    if (tid < BWID && node < NNODE) offs[(size_t)r * (NNODE + 1) + node] = base + excl;
    lcur[tid] = excl;
    __syncthreads();
    for (int j = tid; j < cnt; j += 256) {
        unsigned e = es[j];
        int d = (int)(e >> 16) - lo;
        int p = atomicAdd(&lcur[d], 1);
        stage[p] = (unsigned short)(e & 0xffffu);
    }
    __syncthreads();
    for (int j = tid; j < cnt; j += 256)
        srcs[(size_t)r * NEDGE + base + j] = stage[j];
}

// ---------------------------------------------------------------------------
// Phase-partitioned segment-max gather: iterate PH src-range phases so each
// phase's pooled working set fits per-XCD L2 (4 MB). Max is commutative ->
// identical result; srcs rescans are L1-resident u16.
// ---------------------------------------------------------------------------
template<int F, int PH>
__device__ __forceinline__ void gather_body(
    const unsigned short* __restrict__ pooled, const int* __restrict__ offs,
    const unsigned short* __restrict__ srcs, unsigned short* __restrict__ agg)
{
    const int CG = F / 8;
    int idx = blockIdx.x * 256 + threadIdx.x;
    int n = idx / CG, cg = idx % CG;
    if (n >= NNODE) return;
    int beg = offs[n], end = offs[n + 1];
    unsigned m0 = 0, m1 = 0, m2 = 0, m3 = 0;
    const int step = (NNODE + PH - 1) / PH;
#pragma unroll 1
    for (int ph = 0; ph < PH; ++ph) {
        const int plo = ph * step, phi = plo + step;
        int j = beg;
        for (; j + 4 <= end; j += 4) {
            int s0 = srcs[j], s1 = srcs[j + 1], s2 = srcs[j + 2], s3 = srcs[j + 3];
            if (s0 >= plo && s0 < phi) {
                uint4 v = *(const uint4*)(pooled + (size_t)s0 * F + cg * 8);
                m0 = pk_max_u16(m0, v.x); m1 = pk_max_u16(m1, v.y);
                m2 = pk_max_u16(m2, v.z); m3 = pk_max_u16(m3, v.w);
            }
            if (s1 >= plo && s1 < phi) {
                uint4 v = *(const uint4*)(pooled + (size_t)s1 * F + cg * 8);
                m0 = pk_max_u16(m0, v.x); m1 = pk_max_u16(m1, v.y);
                m2 = pk_max_u16(m2, v.z); m3 = pk_max_u16(m3, v.w);
            }
            if (s2 >= plo && s2 < phi) {
                uint4 v = *(const uint4*)(pooled + (size_t)s2 * F + cg * 8);
                m0 = pk_max_u16(m0, v.x); m1 = pk_max_u16(m1, v.y);
                m2 = pk_max_u16(m2, v.z); m3 = pk_max_u16(m3, v.w);
            }
            if (s3 >= plo && s3 < phi) {
                uint4 v = *(const uint4*)(pooled + (size_t)s3 * F + cg * 8);
                m0 = pk_max_u16(m0, v.x); m1 = pk_max_u16(m1, v.y);
                m2 = pk_max_u16(m2, v.z); m3 = pk_max_u16(m3, v.w);
            }
        }
        for (; j < end; ++j) {
            int s = srcs[j];
            if (s >= plo && s < phi) {
                uint4 v = *(const uint4*)(pooled + (size_t)s * F + cg * 8);
                m0 = pk_max_u16(m0, v.x); m1 = pk_max_u16(m1, v.y);
                m2 = pk_max_u16(m2, v.z); m3 = pk_max_u16(m3, v.w);
            }
        }
    }
    uint4 o; o.x = m0; o.y = m1; o.z = m2; o.w = m3;
    *(uint4*)(agg + (size_t)n * F + cg * 8) = o;
}

// layer 1 (F=128, PH=4): z = 0/1 selects relation of the pair
template<int F>
__global__ __launch_bounds__(256)
void gather2_k(const unsigned short* __restrict__ pooled, const int* __restrict__ offs,
               const unsigned short* __restrict__ srcs, unsigned short* __restrict__ agg,
               int e0, int e1)
{
    const int z = blockIdx.z;
    const int e = z ? e1 : e0;
    gather_body<F, 4>(pooled + (size_t)z * NNODE * F,
                      offs + (size_t)e * (NNODE + 1),
                      srcs + (size_t)e * NEDGE,
                      agg + (size_t)z * NNODE * F);
}

// layers 2/3 (F=64, PH=2): z = relation 0..5; slot z -> regA (z<4) / regB
__global__ __launch_bounds__(256)
void gather6_k(const unsigned short* __restrict__ pooled6, const int* __restrict__ offs,
               const unsigned short* __restrict__ srcs,
               unsigned short* __restrict__ regA, unsigned short* __restrict__ regB)
{
    const int F = 64;
    const int z = blockIdx.z;
    unsigned short* agg = (z < 4) ? regA + (size_t)z * NNODE * F
                                  : regB + (size_t)(z - 4) * NNODE * F;
    gather_body<F, 2>(pooled6 + (size_t)z * NNODE * F,
                      offs + (size_t)z * (NNODE + 1),
                      srcs + (size_t)z * NEDGE,
                      agg);
}

__global__ __launch_bounds__(64)
void fake_k(const unsigned short* __restrict__ mirna, const float* __restrict__ noise,
            const int* __restrict__ t_p, const int* __restrict__ left_p,
            unsigned short* __restrict__ adj_s, float* __restrict__ fake_out)
{
    int r = blockIdx.x, c = threadIdx.x;
    int t = *t_p, left = *left_p;
    int row = left + r;
    float x = bits2f(mirna[(size_t)row * 64 + c]);
    float s = fabsf(x);
#pragma unroll
    for (int off = 32; off > 0; off >>= 1) s += __shfl_down(s, off);
    s = __shfl(s, 0);
    float ab = 1.f;
    for (int i = 0; i <= t; ++i)
        ab *= (1.f - (1e-4f + (0.02f - 1e-4f) * ((float)i / 99.f)));
    float v = sqrtf(ab) * (x / fmaxf(s, 1e-12f)) + sqrtf(1.f - ab) * noise[(size_t)row * 64 + c];
    adj_s[(size_t)r * 4160 + 4096 + c] = f2bits(v);   // fake tail of strided Adj
    fake_out[(size_t)r * 64 + c] = v;
}

// ---------------------------------------------------------------------------
extern "C" void kernel_launch(void* const* d_in, const int* in_sizes, int n_in,
                              void* d_out, int out_size, void* d_ws, size_t ws_size,
                              hipStream_t stream)
{
    const float* h0[3]    = {(const float*)d_in[0], (const float*)d_in[1], (const float*)d_in[2]};
    const float* Wpool[3] = {(const float*)d_in[3], (const float*)d_in[8],  (const float*)d_in[13]};
    const float* bpool[3] = {(const float*)d_in[4], (const float*)d_in[9],  (const float*)d_in[14]};
    const float* bself[3] = {(const float*)d_in[6], (const float*)d_in[11], (const float*)d_in[16]};
    const float* Wself[3] = {(const float*)d_in[5], (const float*)d_in[10], (const float*)d_in[15]};
    const float* Wneigh[3]= {(const float*)d_in[7], (const float*)d_in[12], (const float*)d_in[17]};
    const float* Adj   = (const float*)d_in[18];
    const float* noise = (const float*)d_in[19];
    const float* W1 = (const float*)d_in[20]; const float* b1 = (const float*)d_in[21];
    const float* W2 = (const float*)d_in[22]; const float* b2 = (const float*)d_in[23];
    const float* W3 = (const float*)d_in[24]; const float* b3 = (const float*)d_in[25];
    const float* W4 = (const float*)d_in[26]; const float* b4 = (const float*)d_in[27];
    const int* edges  = (const int*)d_in[28];
    const int* t_p    = (const int*)d_in[29];
    const int* left_p = (const int*)d_in[31];

    // workspace layout (bf16-element offsets); total ~117.8 MB
    unsigned short* ws = (unsigned short*)d_ws;
    const size_t P1 = 0, P2 = 98304, P3 = 122880;
    const size_t FU1 = 147456, FU2 = 245760, FU3 = 294912;   // fused pair weights
    const size_t W1T = 344064, W2T = 1409024, W3T = 1540096, W4T = 2064384;
    const size_t ADJ = 6258688;        // 4096*4160 bf16 (strided, fake tail)
    const size_t POOLED = 23298048;    // 25.6MB region (to HA)
    const size_t HA = 36098048, HB = 45698048;   // 3*50000*64 bf16 each
    int* bcur  = (int*)(ws + 55298048);          // 6*NBKT
    int* bbase = bcur + 6 * NBKT;                // 6*NBKT
    int* offs  = bbase + 6 * NBKT;               // 6*(NNODE+1)
    unsigned short* srcs = (unsigned short*)(offs + 6 * (NNODE + 1)); // 6*NEDGE u16
    unsigned* ebuf = (unsigned*)(ws + POOLED);   // 6*RELEB u32; dead before layer 1
    unsigned short* x1 = ws + POOLED;            // MLP scratch (dead after layer 3)
    unsigned short* x2 = x1 + (size_t)SZ * 256;
    unsigned short* x3 = x2 + (size_t)SZ * 512;
    unsigned short* adj_s = ws + ADJ;
    float* out_fake = (float*)d_out;
    float* out_x    = out_fake + (size_t)SZ * 64;
    // out_x (64MB) as scratch until fake_k:
    unsigned short* hb0 = (unsigned short*)out_x;     // h0 bf16 (38.4MB), layer 1
    unsigned short* agg2_l1 = hb0 + 19200000;         // layer-1 agg2 (25.6MB tail)
    unsigned short* pooled6 = (unsigned short*)out_x; // layers 2/3 pooled (38.4MB)
    unsigned short* aggB6 = pooled6 + 19200000;       // agg slots 4-5 (12.8MB)
    unsigned short* aggA6 = ws + POOLED;              // agg slots 0-3 (25.6MB)
    float* x1p = out_x;                               // MLP1 partials (ZK1*4MB)

    const int SRCr[6] = {0, 1, 0, 2, 2, 1};
    const int PAe[3] = {1, 0, 2}, PBe[3] = {3, 4, 5};   // dst pairs: p -> (eA,eB), dst=p
    dim3 T(256);

    // ---- prep: weight transposes + fused pair weights + conversions ----
    transpose_cvt<<<dim3(4, 4, 6),   T, 0, stream>>>(Wpool[0], nullptr, ws + P1, 128, 0, 128);
    transpose_cvt<<<dim3(2, 2, 6),   T, 0, stream>>>(Wpool[1], nullptr, ws + P2, 64, 0, 64);
    transpose_cvt<<<dim3(2, 2, 6),   T, 0, stream>>>(Wpool[2], nullptr, ws + P3, 64, 0, 64);
    fuse_w_k<<<dim3(4, 2, 3), T, 0, stream>>>(Wself[0], Wneigh[0], ws + FU1, 128);
    fuse_w_k<<<dim3(2, 2, 3), T, 0, stream>>>(Wself[1], Wneigh[1], ws + FU2, 64);
    fuse_w_k<<<dim3(2, 2, 3), T, 0, stream>>>(Wself[2], Wneigh[2], ws + FU3, 64);
    transpose_cvt<<<dim3(130, 8, 1), T, 0, stream>>>(W1, nullptr, ws + W1T, 4160, 0, 256);
    transpose_cvt<<<dim3(8, 16, 1),  T, 0, stream>>>(W2, nullptr, ws + W2T, 256, 0, 512);
    transpose_cvt<<<dim3(16, 32, 1), T, 0, stream>>>(W3, nullptr, ws + W3T, 512, 0, 1024);
    transpose_cvt<<<dim3(32, 128, 1),T, 0, stream>>>(W4, nullptr, ws + W4T, 1024, 0, 4096);
    cvt_adj_k<<<16384, T, 0, stream>>>(Adj, adj_s);
    cvt3_k<<<dim3(6250, 1, 3), T, 0, stream>>>(h0[0], h0[1], h0[2], hb0);

    // ---- CSR build (no global atomic histogram) ----
    binit_k<<<6, T, 0, stream>>>(bcur);
    bucket_k<<<dim3(123, 6), T, 0, stream>>>(edges, bcur, ebuf);
    bscan_k<<<6, T, 0, stream>>>(bcur, bbase, offs);
    debucket_k<<<dim3(NBKT, 6), T, 0, stream>>>(ebuf, bcur, bbase, offs, srcs);

    // ---- layer 1 (hb0 bf16, 128 -> 64), z=2-batched per dst pair ----
    for (int p = 0; p < 3; ++p) {
        const int eA = PAe[p], eB = PBe[p];
        pool2_k<8><<<dim3(1, 782, 2), T, 0, stream>>>(
            hb0 + (size_t)SRCr[eA] * NNODE * 128, hb0 + (size_t)SRCr[eB] * NNODE * 128,
            ws + P1 + (size_t)eA * 16384, ws + P1 + (size_t)eB * 16384,
            bpool[0] + eA * 128, bpool[0] + eB * 128,
            ws + POOLED, NNODE, 128);
        gather2_k<128><<<dim3(3125, 1, 2), T, 0, stream>>>(
            ws + POOLED, offs, srcs, agg2_l1, eA, eB);
        mfma_gemm<4><<<dim3(1, 782), T, 0, stream>>>(
            hb0 + (size_t)p * NNODE * 128, agg2_l1, agg2_l1 + (size_t)NNODE * 128,
            ws + FU1 + (size_t)p * 24576, bself[0] + eA * 64, bself[0] + eB * 64,
            ws + HA + (size_t)p * NNODE * 64, NNODE, 64, 128, 128, 128);
    }

    // ---- layers 2,3 (bf16, 64 -> 64), fully z-batched: 3 dispatches/layer ----
    unsigned short* hin = ws + HA;
    unsigned short* hout = ws + HB;
    for (int layer = 1; layer <= 2; ++layer) {
        const unsigned short* pT = ws + (layer == 1 ? P2 : P3);
        const unsigned short* fT = ws + (layer == 1 ? FU2 : FU3);
        pool6_k<<<dim3(1, 782, 6), T, 0, stream>>>(hin, pT, bpool[layer], pooled6, NNODE);
        gather6_k<<<dim3(1563, 1, 6), T, 0, stream>>>(pooled6, offs, srcs, aggA6, aggB6);
        fused3_k<<<dim3(1, 782, 3), T, 0, stream>>>(hin, aggA6, aggB6, fT,
                                                    bself[layer], hout, NNODE);
        unsigned short* tmp = hin; hin = hout; hout = tmp;
    }
    // hin == ws+HA holds h3; out_x region dead from here

    fake_k<<<SZ, dim3(64), 0, stream>>>(hin, noise, t_p, left_p, adj_s, out_fake);

    // ---- MLP: PIPE=1 (dbuf) for grid-starved layers, PIPE=0 for MLP4 ----
    gemm128<0, 0, 0, 1, 1><<<dim3(2, 32, ZK1), T, 0, stream>>>(
        adj_s, ws + W1T, b1, x1p, SZ, 256, 4160);
    mlp1_ep_k<<<1024, T, 0, stream>>>(x1p, b1, x1);
    gemm128<1, 0, 0, 0, 1><<<dim3(4, 32),  T, 0, stream>>>(x1, ws + W2T, b2, x2, SZ, 512, 256);
    gemm128<1, 0, 0, 0, 1><<<dim3(8, 32),  T, 0, stream>>>(x2, ws + W3T, b3, x3, SZ, 1024, 512);
    gemm128<0, 1, 1, 0, 0><<<dim3(32, 32), T, 0, stream>>>(x3, ws + W4T, b4, out_x, SZ, 4096, 1024);
}

// Round 10
// 884.826 us; speedup vs baseline: 1.2294x; 1.2294x over previous
//
#include <hip/hip_runtime.h>
#include <hip/hip_bf16.h>

#define NNODE 50000
#define NEDGE 500000
#define SZ    4096
#define NBKT  256   // dst-range buckets per relation
#define BWID  196   // dst nodes per bucket: 256*196 = 50176 >= NNODE
#define BCAP  4096  // fixed bucket capacity (expected load 1953 +- 44; 48 sigma)
#define RELEB ((size_t)NBKT * BCAP)
#define ZK1   8     // MLP1 split-K factor (65 k-steps -> 9 per z)

typedef __attribute__((ext_vector_type(8))) short bf16x8;
typedef __attribute__((ext_vector_type(4))) float f32x4;

__device__ __forceinline__ float bits2f(unsigned short u) {
    return __uint_as_float(((unsigned)u) << 16);
}
__device__ __forceinline__ unsigned short f2bits(float f) {  // RNE fp32->bf16
    unsigned x = __float_as_uint(f);
    unsigned r = x + 0x7fffu + ((x >> 16) & 1u);
    return (unsigned short)(r >> 16);
}
__device__ __forceinline__ unsigned pk_max_u16(unsigned a, unsigned b) {
    unsigned lo = max(a & 0xffffu, b & 0xffffu);
    unsigned hi = max(a >> 16, b >> 16);
    return lo | (hi << 16);
}
// async global->LDS, 16B per lane; LDS dest = uniform base + lane*16
__device__ __forceinline__ void gl_lds16(const void* g, void* l) {
    __builtin_amdgcn_global_load_lds(
        (const __attribute__((address_space(1))) unsigned int*)g,
        (__attribute__((address_space(3))) unsigned int*)l, 16, 0, 0);
}

// ---------------------------------------------------------------------------
// Big-GEMM: 128x128 tile, BK=64, 4 waves, linear LDS, global_load_lds w16,
// XCD swizzle. PIPE=1: 2-deep LDS double-buffer (issue next tile before
// computing current) -- use when grid-starved (<~2 blocks/CU); PIPE=0:
// single-buffer 32KB (keeps 4 blocks/CU) -- use when grid fills the GPU.
// PART=1: split-K over gridDim.z, f32 partials to Cv + z*M*N (no bias/act).
// ---------------------------------------------------------------------------
template<int RELU, int SIG, int OUTF32, int PART, int PIPE>
__global__ __launch_bounds__(256)
void gemm128(const unsigned short* __restrict__ A, const unsigned short* __restrict__ Bt,
             const float* __restrict__ bias, void* __restrict__ Cv, int M, int N, int K)
{
    __shared__ unsigned short As[PIPE + 1][128 * 64];
    __shared__ unsigned short Bs[PIPE + 1][128 * 64];
    const int tid = threadIdx.x;
    const int wave = tid >> 6, lane = tid & 63;
    const int m16 = lane & 15, quad = lane >> 4;
    const int wr = wave >> 1, wc = wave & 1;
    // XCD-aware swizzle (bijective: all grids here have nwg % 8 == 0)
    const int nwg = gridDim.x * gridDim.y;
    int bid = blockIdx.y * gridDim.x + blockIdx.x;
    if ((nwg & 7) == 0) { int cpx = nwg >> 3; bid = (bid & 7) * cpx + (bid >> 3); }
    const int bx = bid % gridDim.x, by = bid / gridDim.x;
    const int row0 = by * 128, col0 = bx * 128;
    const int lrow = lane >> 3, lcol = (lane & 7) * 8;

    f32x4 acc[4][4] = {};

    int k0beg = 0, k0end = K;
    if (PART) {
        const int per = ((K >> 6) + gridDim.z - 1) / gridDim.z;
        k0beg = blockIdx.z * per * 64;
        k0end = min(K, k0beg + per * 64);
    }
    const int nt = (k0end - k0beg) >> 6;

    auto STAGE = [&](int b, int k0) {
#pragma unroll
        for (int i = 0; i < 4; ++i) {
            int chunk = wave * 4 + i;           // 16 chunks of 8 rows x 64 elems
            int row = chunk * 8 + lrow;
            gl_lds16(A  + (size_t)(row0 + row) * K + k0 + lcol, &As[b][chunk * 512]);
            gl_lds16(Bt + (size_t)(col0 + row) * K + k0 + lcol, &Bs[b][chunk * 512]);
        }
    };
    auto COMPUTE = [&](int b) {
#pragma unroll
        for (int ks = 0; ks < 2; ++ks) {
            bf16x8 a[4], bb[4];
#pragma unroll
            for (int mt = 0; mt < 4; ++mt)
                a[mt] = *(const bf16x8*)&As[b][(wr * 64 + mt * 16 + m16) * 64 + ks * 32 + quad * 8];
#pragma unroll
            for (int nt2 = 0; nt2 < 4; ++nt2)
                bb[nt2] = *(const bf16x8*)&Bs[b][(wc * 64 + nt2 * 16 + m16) * 64 + ks * 32 + quad * 8];
#pragma unroll
            for (int mt = 0; mt < 4; ++mt)
#pragma unroll
                for (int nt2 = 0; nt2 < 4; ++nt2)
                    acc[mt][nt2] = __builtin_amdgcn_mfma_f32_16x16x32_bf16(a[mt], bb[nt2], acc[mt][nt2], 0, 0, 0);
        }
    };

    if (PIPE) {
        STAGE(0, k0beg);
        __syncthreads();                        // drain prologue loads
        int cur = 0;
        for (int t = 0; t < nt; ++t) {
            if (t + 1 < nt) STAGE(cur ^ 1, k0beg + (t + 1) * 64);  // issue-early
            COMPUTE(cur);
            __syncthreads();                    // next tile arrived + cur free
            cur ^= 1;
        }
    } else {
        for (int t = 0; t < nt; ++t) {
            STAGE(0, k0beg + t * 64);
            __syncthreads();
            COMPUTE(0);
            __syncthreads();
        }
    }

    if (PART) {
        float* P = (float*)Cv + (size_t)blockIdx.z * M * N;
#pragma unroll
        for (int mt = 0; mt < 4; ++mt)
#pragma unroll
            for (int nt2 = 0; nt2 < 4; ++nt2) {
                int gc = col0 + wc * 64 + nt2 * 16 + m16;
#pragma unroll
                for (int r = 0; r < 4; ++r) {
                    int gm = row0 + wr * 64 + mt * 16 + quad * 4 + r;
                    P[(size_t)gm * N + gc] = acc[mt][nt2][r];
                }
            }
        return;
    }

#pragma unroll
    for (int mt = 0; mt < 4; ++mt) {
#pragma unroll
        for (int nt2 = 0; nt2 < 4; ++nt2) {
            int gc = col0 + wc * 64 + nt2 * 16 + m16;
            float bv = bias[gc];
#pragma unroll
            for (int r = 0; r < 4; ++r) {
                int gm = row0 + wr * 64 + mt * 16 + quad * 4 + r;
                size_t idx = (size_t)gm * N + gc;
                float v = acc[mt][nt2][r] + bv;
                if (RELU) v = fmaxf(v, 0.f);
                if (SIG)  v = 1.f / (1.f + __expf(-v));
                if (OUTF32) ((float*)Cv)[idx] = v;
                else        ((unsigned short*)Cv)[idx] = f2bits(v);
            }
        }
    }
}

// split-K reduce + bias + relu + bf16 cvt for MLP layer 1 (ZK1 partials)
__global__ __launch_bounds__(256)
void mlp1_ep_k(const float* __restrict__ p, const float* __restrict__ b1,
               unsigned short* __restrict__ x1)
{
    const size_t MN = (size_t)SZ * 256;
    int i = blockIdx.x * 256 + threadIdx.x;            // float4 groups
    if (i >= (int)(MN / 4)) return;
    float4 s = ((const float4*)p)[i];
#pragma unroll
    for (int z = 1; z < ZK1; ++z) {
        float4 a = ((const float4*)(p + (size_t)z * MN))[i];
        s.x += a.x; s.y += a.y; s.z += a.z; s.w += a.w;
    }
    int base = i * 4;
    ushort4 o;
    o.x = f2bits(fmaxf(s.x + b1[(base + 0) & 255], 0.f));
    o.y = f2bits(fmaxf(s.y + b1[(base + 1) & 255], 0.f));
    o.z = f2bits(fmaxf(s.z + b1[(base + 2) & 255], 0.f));
    o.w = f2bits(fmaxf(s.w + b1[(base + 3) & 255], 0.f));
    ((ushort4*)x1)[i] = o;
}

// ---------------------------------------------------------------------------
// Paired pool GEMM (layer 1): z = 0/1 selects (A, Bt, bias); out slot z*M*N.
// ---------------------------------------------------------------------------
template<int NT>
__global__ __launch_bounds__(256)
void pool2_k(const unsigned short* __restrict__ A0, const unsigned short* __restrict__ A1,
             const unsigned short* __restrict__ Bt0, const unsigned short* __restrict__ Bt1,
             const float* __restrict__ b0, const float* __restrict__ b1,
             unsigned short* __restrict__ out, int M, int K)
{
    __shared__ unsigned short As[64][72];
    __shared__ unsigned short Bs[NT * 16][72];
    const int z = blockIdx.z;
    const unsigned short* A = z ? A1 : A0;
    const unsigned short* Bt = z ? Bt1 : Bt0;
    const float* bias = z ? b1 : b0;
    const int N = NT * 16;
    unsigned short* Cv = out + (size_t)z * M * N;

    const int tid = threadIdx.x;
    const int wave = tid >> 6, lane = tid & 63;
    const int m16 = lane & 15, quad = lane >> 4;
    const int row0 = blockIdx.y * 64, col0 = blockIdx.x * N;

    f32x4 acc[NT] = {};

    for (int k0 = 0; k0 < K; k0 += 64) {
#pragma unroll
        for (int it = 0; it < 2; ++it) {
            int u = tid + it * 256;
            int m = u >> 3, c = (u & 7) * 8;
            int gm = row0 + m;
            uint4 v = make_uint4(0u, 0u, 0u, 0u);
            if (gm < M) v = *(const uint4*)(A + (size_t)gm * K + k0 + c);
            *(uint4*)&As[m][c] = v;
        }
#pragma unroll
        for (int it = 0; it < NT / 2; ++it) {
            int u = tid + it * 256;
            int n = u >> 3, c = (u & 7) * 8;
            uint4 v = *(const uint4*)(Bt + (size_t)(col0 + n) * K + k0 + c);
            *(uint4*)&Bs[n][c] = v;
        }
        __syncthreads();
#pragma unroll
        for (int ks = 0; ks < 2; ++ks) {
            bf16x8 a = *(const bf16x8*)&As[wave * 16 + m16][ks * 32 + quad * 8];
#pragma unroll
            for (int nt = 0; nt < NT; ++nt) {
                bf16x8 b = *(const bf16x8*)&Bs[nt * 16 + m16][ks * 32 + quad * 8];
                acc[nt] = __builtin_amdgcn_mfma_f32_16x16x32_bf16(a, b, acc[nt], 0, 0, 0);
            }
        }
        __syncthreads();
    }

#pragma unroll
    for (int nt = 0; nt < NT; ++nt) {
        int gc = col0 + nt * 16 + m16;
        float bv = bias[gc];
#pragma unroll
        for (int r = 0; r < 4; ++r) {
            int gm = row0 + wave * 16 + quad * 4 + r;
            if (gm < M)
                Cv[(size_t)gm * N + gc] = f2bits(fmaxf(acc[nt][r] + bv, 0.f));
        }
    }
}

// ---------------------------------------------------------------------------
// All-relation pool GEMM (layers 2/3): z = relation 0..5.
// ---------------------------------------------------------------------------
__global__ __launch_bounds__(256)
void pool6_k(const unsigned short* __restrict__ hin, const unsigned short* __restrict__ pT,
             const float* __restrict__ bp, unsigned short* __restrict__ pooled6, int M)
{
    const int SRCr[6] = {0, 1, 0, 2, 2, 1};
    __shared__ unsigned short As[64][72];
    __shared__ unsigned short Bs[64][72];
    const int z = blockIdx.z;
    const unsigned short* A = hin + (size_t)SRCr[z] * M * 64;
    const unsigned short* Bt = pT + (size_t)z * 4096;
    const float* bias = bp + z * 64;
    unsigned short* Cv = pooled6 + (size_t)z * M * 64;

    const int tid = threadIdx.x;
    const int wave = tid >> 6, lane = tid & 63;
    const int m16 = lane & 15, quad = lane >> 4;
    const int row0 = blockIdx.y * 64;

    f32x4 acc[4] = {};

    {
#pragma unroll
        for (int it = 0; it < 2; ++it) {
            int u = tid + it * 256;
            int m = u >> 3, c = (u & 7) * 8;
            int gm = row0 + m;
            uint4 v = make_uint4(0u, 0u, 0u, 0u);
            if (gm < M) v = *(const uint4*)(A + (size_t)gm * 64 + c);
            *(uint4*)&As[m][c] = v;
        }
#pragma unroll
        for (int it = 0; it < 2; ++it) {
            int u = tid + it * 256;
            int n = u >> 3, c = (u & 7) * 8;
            uint4 v = *(const uint4*)(Bt + (size_t)n * 64 + c);
            *(uint4*)&Bs[n][c] = v;
        }
        __syncthreads();
#pragma unroll
        for (int ks = 0; ks < 2; ++ks) {
            bf16x8 a = *(const bf16x8*)&As[wave * 16 + m16][ks * 32 + quad * 8];
#pragma unroll
            for (int nt = 0; nt < 4; ++nt) {
                bf16x8 b = *(const bf16x8*)&Bs[nt * 16 + m16][ks * 32 + quad * 8];
                acc[nt] = __builtin_amdgcn_mfma_f32_16x16x32_bf16(a, b, acc[nt], 0, 0, 0);
            }
        }
    }

#pragma unroll
    for (int nt = 0; nt < 4; ++nt) {
        int gc = nt * 16 + m16;
        float bv = bias[gc];
#pragma unroll
        for (int r = 0; r < 4; ++r) {
            int gm = row0 + wave * 16 + quad * 4 + r;
            if (gm < M)
                Cv[(size_t)gm * 64 + gc] = f2bits(fmaxf(acc[nt][r] + bv, 0.f));
        }
    }
}

// ---------------------------------------------------------------------------
// Fused dst-pair GEMM (layer 1 pair version).
// ---------------------------------------------------------------------------
template<int NT>
__global__ __launch_bounds__(256)
void mfma_gemm(const unsigned short* __restrict__ A1, const unsigned short* __restrict__ A2,
               const unsigned short* __restrict__ A3,
               const unsigned short* __restrict__ Bt, const float* __restrict__ bias,
               const float* __restrict__ bias2,
               unsigned short* __restrict__ Cv, int M, int N, int Ka, int Kb, int Kc)
{
    __shared__ unsigned short As[64][72];
    __shared__ unsigned short Bs[NT * 16][72];
    const int tid = threadIdx.x;
    const int wave = tid >> 6, lane = tid & 63;
    const int m16 = lane & 15, quad = lane >> 4;
    const int row0 = blockIdx.y * 64, col0 = blockIdx.x * (NT * 16);
    const int K = Ka + Kb + Kc;

    f32x4 acc[NT] = {};

    for (int k0 = 0; k0 < K; k0 += 64) {
        const int seg = (k0 >= Ka + Kb) ? 2 : ((k0 >= Ka) ? 1 : 0);
        const unsigned short* src = seg == 2 ? A3 : (seg == 1 ? A2 : A1);
        const int ld = seg == 2 ? Kc : (seg == 1 ? Kb : Ka);
        const int kb = k0 - (seg == 2 ? Ka + Kb : (seg == 1 ? Ka : 0));
#pragma unroll
        for (int it = 0; it < 2; ++it) {
            int u = tid + it * 256;
            int m = u >> 3, c = (u & 7) * 8;
            int gm = row0 + m;
            uint4 v = make_uint4(0u, 0u, 0u, 0u);
            if (gm < M) v = *(const uint4*)(src + (size_t)gm * ld + kb + c);
            *(uint4*)&As[m][c] = v;
        }
#pragma unroll
        for (int it = 0; it < NT / 2; ++it) {
            int u = tid + it * 256;
            int n = u >> 3, c = (u & 7) * 8;
            uint4 v = *(const uint4*)(Bt + (size_t)(col0 + n) * K + k0 + c);
            *(uint4*)&Bs[n][c] = v;
        }
        __syncthreads();
#pragma unroll
        for (int ks = 0; ks < 2; ++ks) {
            bf16x8 a = *(const bf16x8*)&As[wave * 16 + m16][ks * 32 + quad * 8];
#pragma unroll
            for (int nt = 0; nt < NT; ++nt) {
                bf16x8 b = *(const bf16x8*)&Bs[nt * 16 + m16][ks * 32 + quad * 8];
                acc[nt] = __builtin_amdgcn_mfma_f32_16x16x32_bf16(a, b, acc[nt], 0, 0, 0);
            }
        }
        __syncthreads();
    }

#pragma unroll
    for (int nt = 0; nt < NT; ++nt) {
        int gc = col0 + nt * 16 + m16;
        float bv = bias[gc] + bias2[gc];
#pragma unroll
        for (int r = 0; r < 4; ++r) {
            int gm = row0 + wave * 16 + quad * 4 + r;
            if (gm < M)
                Cv[(size_t)gm * N + gc] = f2bits(acc[nt][r] + bv);
        }
    }
}

// ---------------------------------------------------------------------------
// All-pairs fused GEMM (layers 2/3): z = dst pair 0..2, K = 192.
// ---------------------------------------------------------------------------
__global__ __launch_bounds__(256)
void fused3_k(const unsigned short* __restrict__ hin,
              const unsigned short* __restrict__ regA, const unsigned short* __restrict__ regB,
              const unsigned short* __restrict__ fT, const float* __restrict__ bs,
              unsigned short* __restrict__ hout, int M)
{
    const int PAe[3] = {1, 0, 2}, PBe[3] = {3, 4, 5};
    __shared__ unsigned short As[64][72];
    __shared__ unsigned short Bs[64][72];
    const int z = blockIdx.z;
    const int eA = PAe[z], eB = PBe[z];
    const unsigned short* A1 = hin + (size_t)z * M * 64;
    const unsigned short* A2 = (eA < 4) ? regA + (size_t)eA * M * 64 : regB + (size_t)(eA - 4) * M * 64;
    const unsigned short* A3 = (eB < 4) ? regA + (size_t)eB * M * 64 : regB + (size_t)(eB - 4) * M * 64;
    const unsigned short* Bt = fT + (size_t)z * 12288;
    const float* bias = bs + eA * 64;
    const float* bias2 = bs + eB * 64;
    unsigned short* Cv = hout + (size_t)z * M * 64;

    const int tid = threadIdx.x;
    const int wave = tid >> 6, lane = tid & 63;
    const int m16 = lane & 15, quad = lane >> 4;
    const int row0 = blockIdx.y * 64;

    f32x4 acc[4] = {};

#pragma unroll
    for (int seg = 0; seg < 3; ++seg) {
        const unsigned short* src = seg == 2 ? A3 : (seg == 1 ? A2 : A1);
        const int k0 = seg * 64;
#pragma unroll
        for (int it = 0; it < 2; ++it) {
            int u = tid + it * 256;
            int m = u >> 3, c = (u & 7) * 8;
            int gm = row0 + m;
            uint4 v = make_uint4(0u, 0u, 0u, 0u);
            if (gm < M) v = *(const uint4*)(src + (size_t)gm * 64 + c);
            *(uint4*)&As[m][c] = v;
        }
#pragma unroll
        for (int it = 0; it < 2; ++it) {
            int u = tid + it * 256;
            int n = u >> 3, c = (u & 7) * 8;
            uint4 v = *(const uint4*)(Bt + (size_t)n * 192 + k0 + c);
            *(uint4*)&Bs[n][c] = v;
        }
        __syncthreads();
#pragma unroll
        for (int ks = 0; ks < 2; ++ks) {
            bf16x8 a = *(const bf16x8*)&As[wave * 16 + m16][ks * 32 + quad * 8];
#pragma unroll
            for (int nt = 0; nt < 4; ++nt) {
                bf16x8 b = *(const bf16x8*)&Bs[nt * 16 + m16][ks * 32 + quad * 8];
                acc[nt] = __builtin_amdgcn_mfma_f32_16x16x32_bf16(a, b, acc[nt], 0, 0, 0);
            }
        }
        __syncthreads();
    }

#pragma unroll
    for (int nt = 0; nt < 4; ++nt) {
        int gc = nt * 16 + m16;
        float bv = bias[gc] + bias2[gc];
#pragma unroll
        for (int r = 0; r < 4; ++r) {
            int gm = row0 + wave * 16 + quad * 4 + r;
            if (gm < M)
                Cv[(size_t)gm * 64 + gc] = f2bits(acc[nt][r] + bv);
        }
    }
}

// ---------------------------------------------------------------------------
__global__ __launch_bounds__(256)
void transpose_cvt(const float* __restrict__ src1, const float* __restrict__ src2,
                   unsigned short* __restrict__ dst, int R1, int R2, int Nn)
{
    __shared__ float tile[32][33];
    const int R = R1 + R2;
    const int e = blockIdx.z;
    src1 += (size_t)e * R1 * Nn;
    if (src2) src2 += (size_t)e * R2 * Nn;
    dst += (size_t)e * Nn * R;
    const int r0 = blockIdx.x * 32, n0 = blockIdx.y * 32;
    const int lr = threadIdx.x >> 5, ln = threadIdx.x & 31;
#pragma unroll
    for (int i = 0; i < 4; ++i) {
        int r = r0 + lr + i * 8, n = n0 + ln;
        float v = 0.f;
        if (r < R && n < Nn) v = (r < R1) ? src1[(size_t)r * Nn + n]
                                          : src2[(size_t)(r - R1) * Nn + n];
        tile[lr + i * 8][ln] = v;
    }
    __syncthreads();
#pragma unroll
    for (int i = 0; i < 4; ++i) {
        int n = n0 + lr + i * 8, r = r0 + ln;
        if (n < Nn && r < R) dst[(size_t)n * R + r] = f2bits(tile[ln][lr + i * 8]);
    }
}

// fused self+neigh weight prep for dst pair p: Bt[p] = [T(Ws[eA]+Ws[eB]) |
// T(Wn[eA]) | T(Wn[eB])] as [64][3F] bf16.  pairs by dst: (1,3),(0,4),(2,5)
__global__ __launch_bounds__(256)
void fuse_w_k(const float* __restrict__ Ws, const float* __restrict__ Wn,
              unsigned short* __restrict__ dst, int F)
{
    const int PAe[3] = {1, 0, 2}, PBe[3] = {3, 4, 5};
    __shared__ float tile[32][33];
    const int p = blockIdx.z;
    const int eA = PAe[p], eB = PBe[p];
    const int Kt = 3 * F;
    unsigned short* D = dst + (size_t)p * 64 * Kt;
    const int r0 = blockIdx.x * 32;       // over F
    const int n0 = blockIdx.y * 32;       // over 64 out-cols
    const int lr = threadIdx.x >> 5, ln = threadIdx.x & 31;
    for (int seg = 0; seg < 3; ++seg) {
        __syncthreads();
#pragma unroll
        for (int i = 0; i < 4; ++i) {
            int r = r0 + lr + i * 8, n = n0 + ln;
            float v;
            if (seg == 0)
                v = Ws[((size_t)eA * F + r) * 64 + n] + Ws[((size_t)eB * F + r) * 64 + n];
            else if (seg == 1)
                v = Wn[((size_t)eA * F + r) * 64 + n];
            else
                v = Wn[((size_t)eB * F + r) * 64 + n];
            tile[lr + i * 8][ln] = v;
        }
        __syncthreads();
        const int koff = seg * F;
#pragma unroll
        for (int i = 0; i < 4; ++i) {
            int n = n0 + lr + i * 8, r = r0 + ln;
            D[(size_t)n * Kt + koff + r] = f2bits(tile[ln][lr + i * 8]);
        }
    }
}

// 3 h0 feature matrices -> bf16, batched over z
__global__ __launch_bounds__(256)
void cvt3_k(const float* __restrict__ s0, const float* __restrict__ s1,
            const float* __restrict__ s2, unsigned short* __restrict__ dst)
{
    const int z = blockIdx.z;
    const float* src = z == 0 ? s0 : (z == 1 ? s1 : s2);
    dst += (size_t)z * NNODE * 128;
    int i = blockIdx.x * 256 + threadIdx.x;
    if (i >= 1600000) return;
    float4 v = ((const float4*)src)[i];
    ushort4 w;
    w.x = f2bits(v.x); w.y = f2bits(v.y); w.z = f2bits(v.z); w.w = f2bits(v.w);
    ((ushort4*)dst)[i] = w;
}

// Adj fp32 [4096][4096] -> bf16 strided [4096][4160] (fake tail filled later)
__global__ __launch_bounds__(256)
void cvt_adj_k(const float* __restrict__ src, unsigned short* __restrict__ dst)
{
    int i = blockIdx.x * 256 + threadIdx.x;           // 4,194,304 float4 groups
    if (i >= 4194304) return;
    int r = i >> 10, c4 = i & 1023;
    float4 v = ((const float4*)src)[i];
    ushort4 w;
    w.x = f2bits(v.x); w.y = f2bits(v.y); w.z = f2bits(v.z); w.w = f2bits(v.w);
    *(ushort4*)(dst + (size_t)r * 4160 + c4 * 4) = w;
}

// ---------------------------------------------------------------------------
// CSR build, atomic-histogram-free.
// ---------------------------------------------------------------------------
__global__ __launch_bounds__(256)
void binit_k(int* __restrict__ bcur)
{
    bcur[blockIdx.x * NBKT + threadIdx.x] = threadIdx.x * BCAP;
}

__global__ __launch_bounds__(256)
void bucket_k(const int* __restrict__ edges, int* __restrict__ bcur,
              unsigned* __restrict__ ebuf)
{
    const int r = blockIdx.y;
    const int base = blockIdx.x * 4096;
    const int tid = threadIdx.x;
    __shared__ int lcnt[NBKT];
    __shared__ int lbase[NBKT];
    for (int i = tid; i < NBKT; i += 256) lcnt[i] = 0;
    __syncthreads();
    unsigned ent[16];
    int rnk[16];
#pragma unroll
    for (int i = 0; i < 16; ++i) {
        int e = base + tid + i * 256;
        ent[i] = 0xffffffffu;
        rnk[i] = 0;
        if (e < NEDGE) {
            int src = edges[(size_t)r * 2 * NEDGE + e];
            int dst = edges[(size_t)r * 2 * NEDGE + NEDGE + e];
            ent[i] = ((unsigned)dst << 16) | (unsigned)src;
            rnk[i] = atomicAdd(&lcnt[dst / BWID], 1);
        }
    }
    __syncthreads();
    for (int i = tid; i < NBKT; i += 256)
        lbase[i] = lcnt[i] ? atomicAdd(&bcur[r * NBKT + i], lcnt[i]) : 0;
    __syncthreads();
#pragma unroll
    for (int i = 0; i < 16; ++i)
        if (ent[i] != 0xffffffffu) {
            int b = (int)(ent[i] >> 16) / BWID;
            int pos = lbase[b] + rnk[i];
            if (pos < (b + 1) * BCAP)   // statistically unreachable overflow guard
                ebuf[(size_t)r * RELEB + pos] = ent[i];
        }
}

__global__ __launch_bounds__(256)
void bscan_k(const int* __restrict__ bcur, int* __restrict__ bbase,
             int* __restrict__ offs)
{
    const int r = blockIdx.x, tid = threadIdx.x;
    const int lane = tid & 63, wv = tid >> 6;
    int v = bcur[r * NBKT + tid] - tid * BCAP;
    if (v > BCAP) v = BCAP;
    int x = v;
#pragma unroll
    for (int off = 1; off < 64; off <<= 1) {
        int t = __shfl_up(x, off);
        if (lane >= off) x += t;
    }
    __shared__ int wsum[4];
    if (lane == 63) wsum[wv] = x;
    __syncthreads();
    int add = 0;
#pragma unroll
    for (int w = 0; w < 4; ++w) if (w < wv) add += wsum[w];
    x += add;
    bbase[r * NBKT + tid] = x - v;
    if (tid == 255) offs[(size_t)r * (NNODE + 1) + NNODE] = x;
}

__global__ __launch_bounds__(256)
void debucket_k(const unsigned* __restrict__ ebuf, const int* __restrict__ bcur,
                const int* __restrict__ bbase, int* __restrict__ offs,
                unsigned short* __restrict__ srcs)
{
    const int r = blockIdx.y, b = blockIdx.x, tid = threadIdx.x;
    const int lo = b * BWID;
    __shared__ unsigned es[BCAP];
    __shared__ unsigned short stage[BCAP];
    __shared__ int lhist[256];
    __shared__ int buf[256];
    __shared__ int lcur[256];
    int cnt = bcur[r * NBKT + b] - b * BCAP;
    if (cnt > BCAP) cnt = BCAP;
    const int base = bbase[r * NBKT + b];
    lhist[tid] = 0;
    __syncthreads();
    for (int j = tid; j < cnt; j += 256) {
        unsigned e = ebuf[(size_t)r * RELEB + (size_t)b * BCAP + j];
        es[j] = e;
        atomicAdd(&lhist[(int)(e >> 16) - lo], 1);
    }
    __syncthreads();
    int v = lhist[tid];
    buf[tid] = v;
    __syncthreads();
    for (int off = 1; off < 256; off <<= 1) {
        int t = (tid >= off) ? buf[tid - off] : 0;
        __syncthreads();
        buf[tid] += t;
        __syncthreads();
    }
    int excl = buf[tid] - v;
    int node = lo + tid;
    if (tid < BWID && node < NNODE) offs[(size_t)r * (NNODE + 1) + node] = base + excl;
    lcur[tid] = excl;
    __syncthreads();
    for (int j = tid; j < cnt; j += 256) {
        unsigned e = es[j];
        int d = (int)(e >> 16) - lo;
        int p = atomicAdd(&lcur[d], 1);
        stage[p] = (unsigned short)(e & 0xffffu);
    }
    __syncthreads();
    for (int j = tid; j < cnt; j += 256)
        srcs[(size_t)r * NEDGE + base + j] = stage[j];
}

// ---------------------------------------------------------------------------
// Paired segment-max gather, layer 1 (F=128): z = 0/1 selects relation.
// 4-wide unconditional unroll (4 independent loads in flight).
// ---------------------------------------------------------------------------
template<int F>
__global__ __launch_bounds__(256)
void gather2_k(const unsigned short* __restrict__ pooled, const int* __restrict__ offs,
               const unsigned short* __restrict__ srcs, unsigned short* __restrict__ agg,
               int e0, int e1)
{
    const int CG = F / 8;
    const int z = blockIdx.z;
    const int e = z ? e1 : e0;
    pooled += (size_t)z * NNODE * F;
    agg    += (size_t)z * NNODE * F;
    offs   += (size_t)e * (NNODE + 1);
    srcs   += (size_t)e * NEDGE;
    int idx = blockIdx.x * 256 + threadIdx.x;
    int n = idx / CG, cg = idx % CG;
    if (n >= NNODE) return;
    int beg = offs[n], end = offs[n + 1];
    unsigned m0 = 0, m1 = 0, m2 = 0, m3 = 0;
    int j = beg;
    for (; j + 4 <= end; j += 4) {
        int s0 = srcs[j], s1 = srcs[j + 1], s2 = srcs[j + 2], s3 = srcs[j + 3];
        uint4 v0 = *(const uint4*)(pooled + (size_t)s0 * F + cg * 8);
        uint4 v1 = *(const uint4*)(pooled + (size_t)s1 * F + cg * 8);
        uint4 v2 = *(const uint4*)(pooled + (size_t)s2 * F + cg * 8);
        uint4 v3 = *(const uint4*)(pooled + (size_t)s3 * F + cg * 8);
        m0 = pk_max_u16(m0, pk_max_u16(pk_max_u16(v0.x, v1.x), pk_max_u16(v2.x, v3.x)));
        m1 = pk_max_u16(m1, pk_max_u16(pk_max_u16(v0.y, v1.y), pk_max_u16(v2.y, v3.y)));
        m2 = pk_max_u16(m2, pk_max_u16(pk_max_u16(v0.z, v1.z), pk_max_u16(v2.z, v3.z)));
        m3 = pk_max_u16(m3, pk_max_u16(pk_max_u16(v0.w, v1.w), pk_max_u16(v2.w, v3.w)));
    }
    for (; j < end; ++j) {
        int s = srcs[j];
        uint4 v = *(const uint4*)(pooled + (size_t)s * F + cg * 8);
        m0 = pk_max_u16(m0, v.x);
        m1 = pk_max_u16(m1, v.y);
        m2 = pk_max_u16(m2, v.z);
        m3 = pk_max_u16(m3, v.w);
    }
    uint4 o; o.x = m0; o.y = m1; o.z = m2; o.w = m3;
    *(uint4*)(agg + (size_t)n * F + cg * 8) = o;
}

// ---------------------------------------------------------------------------
// All-relation segment-max gather (layers 2/3, F=64): z = relation 0..5.
// ---------------------------------------------------------------------------
__global__ __launch_bounds__(256)
void gather6_k(const unsigned short* __restrict__ pooled6, const int* __restrict__ offs,
               const unsigned short* __restrict__ srcs,
               unsigned short* __restrict__ regA, unsigned short* __restrict__ regB)
{
    const int F = 64, CG = 8;
    const int z = blockIdx.z;
    const unsigned short* pooled = pooled6 + (size_t)z * NNODE * F;
    unsigned short* agg = (z < 4) ? regA + (size_t)z * NNODE * F
                                  : regB + (size_t)(z - 4) * NNODE * F;
    offs += (size_t)z * (NNODE + 1);
    srcs += (size_t)z * NEDGE;
    int idx = blockIdx.x * 256 + threadIdx.x;
    int n = idx / CG, cg = idx % CG;
    if (n >= NNODE) return;
    int beg = offs[n], end = offs[n + 1];
    unsigned m0 = 0, m1 = 0, m2 = 0, m3 = 0;
    int j = beg;
    for (; j + 4 <= end; j += 4) {
        int s0 = srcs[j], s1 = srcs[j + 1], s2 = srcs[j + 2], s3 = srcs[j + 3];
        uint4 v0 = *(const uint4*)(pooled + (size_t)s0 * F + cg * 8);
        uint4 v1 = *(const uint4*)(pooled + (size_t)s1 * F + cg * 8);
        uint4 v2 = *(const uint4*)(pooled + (size_t)s2 * F + cg * 8);
        uint4 v3 = *(const uint4*)(pooled + (size_t)s3 * F + cg * 8);
        m0 = pk_max_u16(m0, pk_max_u16(pk_max_u16(v0.x, v1.x), pk_max_u16(v2.x, v3.x)));
        m1 = pk_max_u16(m1, pk_max_u16(pk_max_u16(v0.y, v1.y), pk_max_u16(v2.y, v3.y)));
        m2 = pk_max_u16(m2, pk_max_u16(pk_max_u16(v0.z, v1.z), pk_max_u16(v2.z, v3.z)));
        m3 = pk_max_u16(m3, pk_max_u16(pk_max_u16(v0.w, v1.w), pk_max_u16(v2.w, v3.w)));
    }
    for (; j < end; ++j) {
        int s = srcs[j];
        uint4 v = *(const uint4*)(pooled + (size_t)s * F + cg * 8);
        m0 = pk_max_u16(m0, v.x);
        m1 = pk_max_u16(m1, v.y);
        m2 = pk_max_u16(m2, v.z);
        m3 = pk_max_u16(m3, v.w);
    }
    uint4 o; o.x = m0; o.y = m1; o.z = m2; o.w = m3;
    *(uint4*)(agg + (size_t)n * F + cg * 8) = o;
}

__global__ __launch_bounds__(64)
void fake_k(const unsigned short* __restrict__ mirna, const float* __restrict__ noise,
            const int* __restrict__ t_p, const int* __restrict__ left_p,
            unsigned short* __restrict__ adj_s, float* __restrict__ fake_out)
{
    int r = blockIdx.x, c = threadIdx.x;
    int t = *t_p, left = *left_p;
    int row = left + r;
    float x = bits2f(mirna[(size_t)row * 64 + c]);
    float s = fabsf(x);
#pragma unroll
    for (int off = 32; off > 0; off >>= 1) s += __shfl_down(s, off);
    s = __shfl(s, 0);
    float ab = 1.f;
    for (int i = 0; i <= t; ++i)
        ab *= (1.f - (1e-4f + (0.02f - 1e-4f) * ((float)i / 99.f)));
    float v = sqrtf(ab) * (x / fmaxf(s, 1e-12f)) + sqrtf(1.f - ab) * noise[(size_t)row * 64 + c];
    adj_s[(size_t)r * 4160 + 4096 + c] = f2bits(v);   // fake tail of strided Adj
    fake_out[(size_t)r * 64 + c] = v;
}

// ---------------------------------------------------------------------------
extern "C" void kernel_launch(void* const* d_in, const int* in_sizes, int n_in,
                              void* d_out, int out_size, void* d_ws, size_t ws_size,
                              hipStream_t stream)
{
    const float* h0[3]    = {(const float*)d_in[0], (const float*)d_in[1], (const float*)d_in[2]};
    const float* Wpool[3] = {(const float*)d_in[3], (const float*)d_in[8],  (const float*)d_in[13]};
    const float* bpool[3] = {(const float*)d_in[4], (const float*)d_in[9],  (const float*)d_in[14]};
    const float* bself[3] = {(const float*)d_in[6], (const float*)d_in[11], (const float*)d_in[16]};
    const float* Wself[3] = {(const float*)d_in[5], (const float*)d_in[10], (const float*)d_in[15]};
    const float* Wneigh[3]= {(const float*)d_in[7], (const float*)d_in[12], (const float*)d_in[17]};
    const float* Adj   = (const float*)d_in[18];
    const float* noise = (const float*)d_in[19];
    const float* W1 = (const float*)d_in[20]; const float* b1 = (const float*)d_in[21];
    const float* W2 = (const float*)d_in[22]; const float* b2 = (const float*)d_in[23];
    const float* W3 = (const float*)d_in[24]; const float* b3 = (const float*)d_in[25];
    const float* W4 = (const float*)d_in[26]; const float* b4 = (const float*)d_in[27];
    const int* edges  = (const int*)d_in[28];
    const int* t_p    = (const int*)d_in[29];
    const int* left_p = (const int*)d_in[31];

    // workspace layout (bf16-element offsets); total ~117.8 MB
    unsigned short* ws = (unsigned short*)d_ws;
    const size_t P1 = 0, P2 = 98304, P3 = 122880;
    const size_t FU1 = 147456, FU2 = 245760, FU3 = 294912;   // fused pair weights
    const size_t W1T = 344064, W2T = 1409024, W3T = 1540096, W4T = 2064384;
    const size_t ADJ = 6258688;        // 4096*4160 bf16 (strided, fake tail)
    const size_t POOLED = 23298048;    // 25.6MB region (to HA)
    const size_t HA = 36098048, HB = 45698048;   // 3*50000*64 bf16 each
    int* bcur  = (int*)(ws + 55298048);          // 6*NBKT
    int* bbase = bcur + 6 * NBKT;                // 6*NBKT
    int* offs  = bbase + 6 * NBKT;               // 6*(NNODE+1)
    unsigned short* srcs = (unsigned short*)(offs + 6 * (NNODE + 1)); // 6*NEDGE u16
    unsigned* ebuf = (unsigned*)(ws + POOLED);   // 6*RELEB u32; dead before layer 1
    unsigned short* x1 = ws + POOLED;            // MLP scratch (dead after layer 3)
    unsigned short* x2 = x1 + (size_t)SZ * 256;
    unsigned short* x3 = x2 + (size_t)SZ * 512;
    unsigned short* adj_s = ws + ADJ;
    float* out_fake = (float*)d_out;
    float* out_x    = out_fake + (size_t)SZ * 64;
    // out_x (64MB) as scratch until fake_k:
    unsigned short* hb0 = (unsigned short*)out_x;     // h0 bf16 (38.4MB), layer 1
    unsigned short* agg2_l1 = hb0 + 19200000;         // layer-1 agg2 (25.6MB tail)
    unsigned short* pooled6 = (unsigned short*)out_x; // layers 2/3 pooled (38.4MB)
    unsigned short* aggB6 = pooled6 + 19200000;       // agg slots 4-5 (12.8MB)
    unsigned short* aggA6 = ws + POOLED;              // agg slots 0-3 (25.6MB)
    float* x1p = out_x;                               // MLP1 partials (ZK1*4MB)

    const int SRCr[6] = {0, 1, 0, 2, 2, 1};
    const int PAe[3] = {1, 0, 2}, PBe[3] = {3, 4, 5};   // dst pairs: p -> (eA,eB), dst=p
    dim3 T(256);

    // ---- prep: weight transposes + fused pair weights + conversions ----
    transpose_cvt<<<dim3(4, 4, 6),   T, 0, stream>>>(Wpool[0], nullptr, ws + P1, 128, 0, 128);
    transpose_cvt<<<dim3(2, 2, 6),   T, 0, stream>>>(Wpool[1], nullptr, ws + P2, 64, 0, 64);
    transpose_cvt<<<dim3(2, 2, 6),   T, 0, stream>>>(Wpool[2], nullptr, ws + P3, 64, 0, 64);
    fuse_w_k<<<dim3(4, 2, 3), T, 0, stream>>>(Wself[0], Wneigh[0], ws + FU1, 128);
    fuse_w_k<<<dim3(2, 2, 3), T, 0, stream>>>(Wself[1], Wneigh[1], ws + FU2, 64);
    fuse_w_k<<<dim3(2, 2, 3), T, 0, stream>>>(Wself[2], Wneigh[2], ws + FU3, 64);
    transpose_cvt<<<dim3(130, 8, 1), T, 0, stream>>>(W1, nullptr, ws + W1T, 4160, 0, 256);
    transpose_cvt<<<dim3(8, 16, 1),  T, 0, stream>>>(W2, nullptr, ws + W2T, 256, 0, 512);
    transpose_cvt<<<dim3(16, 32, 1), T, 0, stream>>>(W3, nullptr, ws + W3T, 512, 0, 1024);
    transpose_cvt<<<dim3(32, 128, 1),T, 0, stream>>>(W4, nullptr, ws + W4T, 1024, 0, 4096);
    cvt_adj_k<<<16384, T, 0, stream>>>(Adj, adj_s);
    cvt3_k<<<dim3(6250, 1, 3), T, 0, stream>>>(h0[0], h0[1], h0[2], hb0);

    // ---- CSR build (no global atomic histogram) ----
    binit_k<<<6, T, 0, stream>>>(bcur);
    bucket_k<<<dim3(123, 6), T, 0, stream>>>(edges, bcur, ebuf);
    bscan_k<<<6, T, 0, stream>>>(bcur, bbase, offs);
    debucket_k<<<dim3(NBKT, 6), T, 0, stream>>>(ebuf, bcur, bbase, offs, srcs);

    // ---- layer 1 (hb0 bf16, 128 -> 64), z=2-batched per dst pair ----
    for (int p = 0; p < 3; ++p) {
        const int eA = PAe[p], eB = PBe[p];
        pool2_k<8><<<dim3(1, 782, 2), T, 0, stream>>>(
            hb0 + (size_t)SRCr[eA] * NNODE * 128, hb0 + (size_t)SRCr[eB] * NNODE * 128,
            ws + P1 + (size_t)eA * 16384, ws + P1 + (size_t)eB * 16384,
            bpool[0] + eA * 128, bpool[0] + eB * 128,
            ws + POOLED, NNODE, 128);
        gather2_k<128><<<dim3(3125, 1, 2), T, 0, stream>>>(
            ws + POOLED, offs, srcs, agg2_l1, eA, eB);
        mfma_gemm<4><<<dim3(1, 782), T, 0, stream>>>(
            hb0 + (size_t)p * NNODE * 128, agg2_l1, agg2_l1 + (size_t)NNODE * 128,
            ws + FU1 + (size_t)p * 24576, bself[0] + eA * 64, bself[0] + eB * 64,
            ws + HA + (size_t)p * NNODE * 64, NNODE, 64, 128, 128, 128);
    }

    // ---- layers 2,3 (bf16, 64 -> 64), fully z-batched: 3 dispatches/layer ----
    unsigned short* hin = ws + HA;
    unsigned short* hout = ws + HB;
    for (int layer = 1; layer <= 2; ++layer) {
        const unsigned short* pT = ws + (layer == 1 ? P2 : P3);
        const unsigned short* fT = ws + (layer == 1 ? FU2 : FU3);
        pool6_k<<<dim3(1, 782, 6), T, 0, stream>>>(hin, pT, bpool[layer], pooled6, NNODE);
        gather6_k<<<dim3(1563, 1, 6), T, 0, stream>>>(pooled6, offs, srcs, aggA6, aggB6);
        fused3_k<<<dim3(1, 782, 3), T, 0, stream>>>(hin, aggA6, aggB6, fT,
                                                    bself[layer], hout, NNODE);
        unsigned short* tmp = hin; hin = hout; hout = tmp;
    }
    // hin == ws+HA holds h3; out_x region dead from here

    fake_k<<<SZ, dim3(64), 0, stream>>>(hin, noise, t_p, left_p, adj_s, out_fake);

    // ---- MLP: PIPE=1 (dbuf) for grid-starved layers, PIPE=0 for MLP4 ----
    gemm128<0, 0, 0, 1, 1><<<dim3(2, 32, ZK1), T, 0, stream>>>(
        adj_s, ws + W1T, b1, x1p, SZ, 256, 4160);
    mlp1_ep_k<<<1024, T, 0, stream>>>(x1p, b1, x1);
    gemm128<1, 0, 0, 0, 1><<<dim3(4, 32),  T, 0, stream>>>(x1, ws + W2T, b2, x2, SZ, 512, 256);
    gemm128<1, 0, 0, 0, 1><<<dim3(8, 32),  T, 0, stream>>>(x2, ws + W3T, b3, x3, SZ, 1024, 512);
    gemm128<0, 1, 1, 0, 0><<<dim3(32, 32), T, 0, stream>>>(x3, ws + W4T, b4, out_x, SZ, 4096, 1024);
}

// Round 11
// 881.597 us; speedup vs baseline: 1.2339x; 1.0037x over previous
//
#include <hip/hip_runtime.h>
#include <hip/hip_bf16.h>

#define NNODE 50000
#define NEDGE 500000
#define SZ    4096
#define NBKT  256   // dst-range buckets per relation
#define BWID  196   // dst nodes per bucket: 256*196 = 50176 >= NNODE
#define BCAP  4096  // fixed bucket capacity (expected load 1953 +- 44; 48 sigma)
#define RELEB ((size_t)NBKT * BCAP)
#define ZK1   8     // MLP1 split-K factor (65 k-steps -> 9 per z)

typedef __attribute__((ext_vector_type(8))) short bf16x8;
typedef __attribute__((ext_vector_type(4))) float f32x4;

__device__ __forceinline__ float bits2f(unsigned short u) {
    return __uint_as_float(((unsigned)u) << 16);
}
__device__ __forceinline__ unsigned short f2bits(float f) {  // RNE fp32->bf16
    unsigned x = __float_as_uint(f);
    unsigned r = x + 0x7fffu + ((x >> 16) & 1u);
    return (unsigned short)(r >> 16);
}
__device__ __forceinline__ unsigned pk_max_u16(unsigned a, unsigned b) {
    unsigned lo = max(a & 0xffffu, b & 0xffffu);
    unsigned hi = max(a >> 16, b >> 16);
    return lo | (hi << 16);
}
// async global->LDS, 16B per lane; LDS dest = uniform base + lane*16
__device__ __forceinline__ void gl_lds16(const void* g, void* l) {
    __builtin_amdgcn_global_load_lds(
        (const __attribute__((address_space(1))) unsigned int*)g,
        (__attribute__((address_space(3))) unsigned int*)l, 16, 0, 0);
}

// ---------------------------------------------------------------------------
// Big-GEMM: 128x128 tile, BK=64, 4 waves, linear LDS, global_load_lds w16,
// XCD swizzle. PIPE=1: 2-deep LDS double-buffer (grid-starved case);
// PIPE=0: single-buffer 32KB (keeps 4 blocks/CU when grid fills GPU).
// PART=1: split-K over gridDim.z, f32 partials to Cv + z*M*N (no bias/act).
// ---------------------------------------------------------------------------
template<int RELU, int SIG, int OUTF32, int PART, int PIPE>
__global__ __launch_bounds__(256)
void gemm128(const unsigned short* __restrict__ A, const unsigned short* __restrict__ Bt,
             const float* __restrict__ bias, void* __restrict__ Cv, int M, int N, int K)
{
    __shared__ unsigned short As[PIPE + 1][128 * 64];
    __shared__ unsigned short Bs[PIPE + 1][128 * 64];
    const int tid = threadIdx.x;
    const int wave = tid >> 6, lane = tid & 63;
    const int m16 = lane & 15, quad = lane >> 4;
    const int wr = wave >> 1, wc = wave & 1;
    const int nwg = gridDim.x * gridDim.y;
    int bid = blockIdx.y * gridDim.x + blockIdx.x;
    if ((nwg & 7) == 0) { int cpx = nwg >> 3; bid = (bid & 7) * cpx + (bid >> 3); }
    const int bx = bid % gridDim.x, by = bid / gridDim.x;
    const int row0 = by * 128, col0 = bx * 128;
    const int lrow = lane >> 3, lcol = (lane & 7) * 8;

    f32x4 acc[4][4] = {};

    int k0beg = 0, k0end = K;
    if (PART) {
        const int per = ((K >> 6) + gridDim.z - 1) / gridDim.z;
        k0beg = blockIdx.z * per * 64;
        k0end = min(K, k0beg + per * 64);
    }
    const int nt = (k0end - k0beg) >> 6;

    auto STAGE = [&](int b, int k0) {
#pragma unroll
        for (int i = 0; i < 4; ++i) {
            int chunk = wave * 4 + i;
            int row = chunk * 8 + lrow;
            gl_lds16(A  + (size_t)(row0 + row) * K + k0 + lcol, &As[b][chunk * 512]);
            gl_lds16(Bt + (size_t)(col0 + row) * K + k0 + lcol, &Bs[b][chunk * 512]);
        }
    };
    auto COMPUTE = [&](int b) {
#pragma unroll
        for (int ks = 0; ks < 2; ++ks) {
            bf16x8 a[4], bb[4];
#pragma unroll
            for (int mt = 0; mt < 4; ++mt)
                a[mt] = *(const bf16x8*)&As[b][(wr * 64 + mt * 16 + m16) * 64 + ks * 32 + quad * 8];
#pragma unroll
            for (int nt2 = 0; nt2 < 4; ++nt2)
                bb[nt2] = *(const bf16x8*)&Bs[b][(wc * 64 + nt2 * 16 + m16) * 64 + ks * 32 + quad * 8];
#pragma unroll
            for (int mt = 0; mt < 4; ++mt)
#pragma unroll
                for (int nt2 = 0; nt2 < 4; ++nt2)
                    acc[mt][nt2] = __builtin_amdgcn_mfma_f32_16x16x32_bf16(a[mt], bb[nt2], acc[mt][nt2], 0, 0, 0);
        }
    };

    if (PIPE) {
        STAGE(0, k0beg);
        __syncthreads();
        int cur = 0;
        for (int t = 0; t < nt; ++t) {
            if (t + 1 < nt) STAGE(cur ^ 1, k0beg + (t + 1) * 64);
            COMPUTE(cur);
            __syncthreads();
            cur ^= 1;
        }
    } else {
        for (int t = 0; t < nt; ++t) {
            STAGE(0, k0beg + t * 64);
            __syncthreads();
            COMPUTE(0);
            __syncthreads();
        }
    }

    if (PART) {
        float* P = (float*)Cv + (size_t)blockIdx.z * M * N;
#pragma unroll
        for (int mt = 0; mt < 4; ++mt)
#pragma unroll
            for (int nt2 = 0; nt2 < 4; ++nt2) {
                int gc = col0 + wc * 64 + nt2 * 16 + m16;
#pragma unroll
                for (int r = 0; r < 4; ++r) {
                    int gm = row0 + wr * 64 + mt * 16 + quad * 4 + r;
                    P[(size_t)gm * N + gc] = acc[mt][nt2][r];
                }
            }
        return;
    }

#pragma unroll
    for (int mt = 0; mt < 4; ++mt) {
#pragma unroll
        for (int nt2 = 0; nt2 < 4; ++nt2) {
            int gc = col0 + wc * 64 + nt2 * 16 + m16;
            float bv = bias[gc];
#pragma unroll
            for (int r = 0; r < 4; ++r) {
                int gm = row0 + wr * 64 + mt * 16 + quad * 4 + r;
                size_t idx = (size_t)gm * N + gc;
                float v = acc[mt][nt2][r] + bv;
                if (RELU) v = fmaxf(v, 0.f);
                if (SIG)  v = 1.f / (1.f + __expf(-v));
                if (OUTF32) ((float*)Cv)[idx] = v;
                else        ((unsigned short*)Cv)[idx] = f2bits(v);
            }
        }
    }
}

// split-K reduce + bias + relu + bf16 cvt for MLP layer 1 (ZK1 partials)
__global__ __launch_bounds__(256)
void mlp1_ep_k(const float* __restrict__ p, const float* __restrict__ b1,
               unsigned short* __restrict__ x1)
{
    const size_t MN = (size_t)SZ * 256;
    int i = blockIdx.x * 256 + threadIdx.x;
    if (i >= (int)(MN / 4)) return;
    float4 s = ((const float4*)p)[i];
#pragma unroll
    for (int z = 1; z < ZK1; ++z) {
        float4 a = ((const float4*)(p + (size_t)z * MN))[i];
        s.x += a.x; s.y += a.y; s.z += a.z; s.w += a.w;
    }
    int base = i * 4;
    ushort4 o;
    o.x = f2bits(fmaxf(s.x + b1[(base + 0) & 255], 0.f));
    o.y = f2bits(fmaxf(s.y + b1[(base + 1) & 255], 0.f));
    o.z = f2bits(fmaxf(s.z + b1[(base + 2) & 255], 0.f));
    o.w = f2bits(fmaxf(s.w + b1[(base + 3) & 255], 0.f));
    ((ushort4*)x1)[i] = o;
}

// ---------------------------------------------------------------------------
// Paired pool GEMM (layer 1): z = 0/1 selects (A, Bt, bias); out slot z*M*N.
// ---------------------------------------------------------------------------
template<int NT>
__global__ __launch_bounds__(256)
void pool2_k(const unsigned short* __restrict__ A0, const unsigned short* __restrict__ A1,
             const unsigned short* __restrict__ Bt0, const unsigned short* __restrict__ Bt1,
             const float* __restrict__ b0, const float* __restrict__ b1,
             unsigned short* __restrict__ out, int M, int K)
{
    __shared__ unsigned short As[64][72];
    __shared__ unsigned short Bs[NT * 16][72];
    const int z = blockIdx.z;
    const unsigned short* A = z ? A1 : A0;
    const unsigned short* Bt = z ? Bt1 : Bt0;
    const float* bias = z ? b1 : b0;
    const int N = NT * 16;
    unsigned short* Cv = out + (size_t)z * M * N;

    const int tid = threadIdx.x;
    const int wave = tid >> 6, lane = tid & 63;
    const int m16 = lane & 15, quad = lane >> 4;
    const int row0 = blockIdx.y * 64, col0 = blockIdx.x * N;

    f32x4 acc[NT] = {};

    for (int k0 = 0; k0 < K; k0 += 64) {
#pragma unroll
        for (int it = 0; it < 2; ++it) {
            int u = tid + it * 256;
            int m = u >> 3, c = (u & 7) * 8;
            int gm = row0 + m;
            uint4 v = make_uint4(0u, 0u, 0u, 0u);
            if (gm < M) v = *(const uint4*)(A + (size_t)gm * K + k0 + c);
            *(uint4*)&As[m][c] = v;
        }
#pragma unroll
        for (int it = 0; it < NT / 2; ++it) {
            int u = tid + it * 256;
            int n = u >> 3, c = (u & 7) * 8;
            uint4 v = *(const uint4*)(Bt + (size_t)(col0 + n) * K + k0 + c);
            *(uint4*)&Bs[n][c] = v;
        }
        __syncthreads();
#pragma unroll
        for (int ks = 0; ks < 2; ++ks) {
            bf16x8 a = *(const bf16x8*)&As[wave * 16 + m16][ks * 32 + quad * 8];
#pragma unroll
            for (int nt = 0; nt < NT; ++nt) {
                bf16x8 b = *(const bf16x8*)&Bs[nt * 16 + m16][ks * 32 + quad * 8];
                acc[nt] = __builtin_amdgcn_mfma_f32_16x16x32_bf16(a, b, acc[nt], 0, 0, 0);
            }
        }
        __syncthreads();
    }

#pragma unroll
    for (int nt = 0; nt < NT; ++nt) {
        int gc = col0 + nt * 16 + m16;
        float bv = bias[gc];
#pragma unroll
        for (int r = 0; r < 4; ++r) {
            int gm = row0 + wave * 16 + quad * 4 + r;
            if (gm < M)
                Cv[(size_t)gm * N + gc] = f2bits(fmaxf(acc[nt][r] + bv, 0.f));
        }
    }
}

// ---------------------------------------------------------------------------
// All-relation pool GEMM (layers 2/3): z = relation 0..5.
// ---------------------------------------------------------------------------
__global__ __launch_bounds__(256)
void pool6_k(const unsigned short* __restrict__ hin, const unsigned short* __restrict__ pT,
             const float* __restrict__ bp, unsigned short* __restrict__ pooled6, int M)
{
    const int SRCr[6] = {0, 1, 0, 2, 2, 1};
    __shared__ unsigned short As[64][72];
    __shared__ unsigned short Bs[64][72];
    const int z = blockIdx.z;
    const unsigned short* A = hin + (size_t)SRCr[z] * M * 64;
    const unsigned short* Bt = pT + (size_t)z * 4096;
    const float* bias = bp + z * 64;
    unsigned short* Cv = pooled6 + (size_t)z * M * 64;

    const int tid = threadIdx.x;
    const int wave = tid >> 6, lane = tid & 63;
    const int m16 = lane & 15, quad = lane >> 4;
    const int row0 = blockIdx.y * 64;

    f32x4 acc[4] = {};

    {
#pragma unroll
        for (int it = 0; it < 2; ++it) {
            int u = tid + it * 256;
            int m = u >> 3, c = (u & 7) * 8;
            int gm = row0 + m;
            uint4 v = make_uint4(0u, 0u, 0u, 0u);
            if (gm < M) v = *(const uint4*)(A + (size_t)gm * 64 + c);
            *(uint4*)&As[m][c] = v;
        }
#pragma unroll
        for (int it = 0; it < 2; ++it) {
            int u = tid + it * 256;
            int n = u >> 3, c = (u & 7) * 8;
            uint4 v = *(const uint4*)(Bt + (size_t)n * 64 + c);
            *(uint4*)&Bs[n][c] = v;
        }
        __syncthreads();
#pragma unroll
        for (int ks = 0; ks < 2; ++ks) {
            bf16x8 a = *(const bf16x8*)&As[wave * 16 + m16][ks * 32 + quad * 8];
#pragma unroll
            for (int nt = 0; nt < 4; ++nt) {
                bf16x8 b = *(const bf16x8*)&Bs[nt * 16 + m16][ks * 32 + quad * 8];
                acc[nt] = __builtin_amdgcn_mfma_f32_16x16x32_bf16(a, b, acc[nt], 0, 0, 0);
            }
        }
    }

#pragma unroll
    for (int nt = 0; nt < 4; ++nt) {
        int gc = nt * 16 + m16;
        float bv = bias[gc];
#pragma unroll
        for (int r = 0; r < 4; ++r) {
            int gm = row0 + wave * 16 + quad * 4 + r;
            if (gm < M)
                Cv[(size_t)gm * 64 + gc] = f2bits(fmaxf(acc[nt][r] + bv, 0.f));
        }
    }
}

// ---------------------------------------------------------------------------
// Fused dst-pair GEMM (layer 1 pair version).
// ---------------------------------------------------------------------------
template<int NT>
__global__ __launch_bounds__(256)
void mfma_gemm(const unsigned short* __restrict__ A1, const unsigned short* __restrict__ A2,
               const unsigned short* __restrict__ A3,
               const unsigned short* __restrict__ Bt, const float* __restrict__ bias,
               const float* __restrict__ bias2,
               unsigned short* __restrict__ Cv, int M, int N, int Ka, int Kb, int Kc)
{
    __shared__ unsigned short As[64][72];
    __shared__ unsigned short Bs[NT * 16][72];
    const int tid = threadIdx.x;
    const int wave = tid >> 6, lane = tid & 63;
    const int m16 = lane & 15, quad = lane >> 4;
    const int row0 = blockIdx.y * 64, col0 = blockIdx.x * (NT * 16);
    const int K = Ka + Kb + Kc;

    f32x4 acc[NT] = {};

    for (int k0 = 0; k0 < K; k0 += 64) {
        const int seg = (k0 >= Ka + Kb) ? 2 : ((k0 >= Ka) ? 1 : 0);
        const unsigned short* src = seg == 2 ? A3 : (seg == 1 ? A2 : A1);
        const int ld = seg == 2 ? Kc : (seg == 1 ? Kb : Ka);
        const int kb = k0 - (seg == 2 ? Ka + Kb : (seg == 1 ? Ka : 0));
#pragma unroll
        for (int it = 0; it < 2; ++it) {
            int u = tid + it * 256;
            int m = u >> 3, c = (u & 7) * 8;
            int gm = row0 + m;
            uint4 v = make_uint4(0u, 0u, 0u, 0u);
            if (gm < M) v = *(const uint4*)(src + (size_t)gm * ld + kb + c);
            *(uint4*)&As[m][c] = v;
        }
#pragma unroll
        for (int it = 0; it < NT / 2; ++it) {
            int u = tid + it * 256;
            int n = u >> 3, c = (u & 7) * 8;
            uint4 v = *(const uint4*)(Bt + (size_t)(col0 + n) * K + k0 + c);
            *(uint4*)&Bs[n][c] = v;
        }
        __syncthreads();
#pragma unroll
        for (int ks = 0; ks < 2; ++ks) {
            bf16x8 a = *(const bf16x8*)&As[wave * 16 + m16][ks * 32 + quad * 8];
#pragma unroll
            for (int nt = 0; nt < NT; ++nt) {
                bf16x8 b = *(const bf16x8*)&Bs[nt * 16 + m16][ks * 32 + quad * 8];
                acc[nt] = __builtin_amdgcn_mfma_f32_16x16x32_bf16(a, b, acc[nt], 0, 0, 0);
            }
        }
        __syncthreads();
    }

#pragma unroll
    for (int nt = 0; nt < NT; ++nt) {
        int gc = col0 + nt * 16 + m16;
        float bv = bias[gc] + bias2[gc];
#pragma unroll
        for (int r = 0; r < 4; ++r) {
            int gm = row0 + wave * 16 + quad * 4 + r;
            if (gm < M)
                Cv[(size_t)gm * N + gc] = f2bits(acc[nt][r] + bv);
        }
    }
}

// ---------------------------------------------------------------------------
// All-pairs fused GEMM (layers 2/3): z = dst pair 0..2, K = 192.
// ---------------------------------------------------------------------------
__global__ __launch_bounds__(256)
void fused3_k(const unsigned short* __restrict__ hin,
              const unsigned short* __restrict__ regA, const unsigned short* __restrict__ regB,
              const unsigned short* __restrict__ fT, const float* __restrict__ bs,
              unsigned short* __restrict__ hout, int M)
{
    const int PAe[3] = {1, 0, 2}, PBe[3] = {3, 4, 5};
    __shared__ unsigned short As[64][72];
    __shared__ unsigned short Bs[64][72];
    const int z = blockIdx.z;
    const int eA = PAe[z], eB = PBe[z];
    const unsigned short* A1 = hin + (size_t)z * M * 64;
    const unsigned short* A2 = (eA < 4) ? regA + (size_t)eA * M * 64 : regB + (size_t)(eA - 4) * M * 64;
    const unsigned short* A3 = (eB < 4) ? regA + (size_t)eB * M * 64 : regB + (size_t)(eB - 4) * M * 64;
    const unsigned short* Bt = fT + (size_t)z * 12288;
    const float* bias = bs + eA * 64;
    const float* bias2 = bs + eB * 64;
    unsigned short* Cv = hout + (size_t)z * M * 64;

    const int tid = threadIdx.x;
    const int wave = tid >> 6, lane = tid & 63;
    const int m16 = lane & 15, quad = lane >> 4;
    const int row0 = blockIdx.y * 64;

    f32x4 acc[4] = {};

#pragma unroll
    for (int seg = 0; seg < 3; ++seg) {
        const unsigned short* src = seg == 2 ? A3 : (seg == 1 ? A2 : A1);
        const int k0 = seg * 64;
#pragma unroll
        for (int it = 0; it < 2; ++it) {
            int u = tid + it * 256;
            int m = u >> 3, c = (u & 7) * 8;
            int gm = row0 + m;
            uint4 v = make_uint4(0u, 0u, 0u, 0u);
            if (gm < M) v = *(const uint4*)(src + (size_t)gm * 64 + c);
            *(uint4*)&As[m][c] = v;
        }
#pragma unroll
        for (int it = 0; it < 2; ++it) {
            int u = tid + it * 256;
            int n = u >> 3, c = (u & 7) * 8;
            uint4 v = *(const uint4*)(Bt + (size_t)n * 192 + k0 + c);
            *(uint4*)&Bs[n][c] = v;
        }
        __syncthreads();
#pragma unroll
        for (int ks = 0; ks < 2; ++ks) {
            bf16x8 a = *(const bf16x8*)&As[wave * 16 + m16][ks * 32 + quad * 8];
#pragma unroll
            for (int nt = 0; nt < 4; ++nt) {
                bf16x8 b = *(const bf16x8*)&Bs[nt * 16 + m16][ks * 32 + quad * 8];
                acc[nt] = __builtin_amdgcn_mfma_f32_16x16x32_bf16(a, b, acc[nt], 0, 0, 0);
            }
        }
        __syncthreads();
    }

#pragma unroll
    for (int nt = 0; nt < 4; ++nt) {
        int gc = nt * 16 + m16;
        float bv = bias[gc] + bias2[gc];
#pragma unroll
        for (int r = 0; r < 4; ++r) {
            int gm = row0 + wave * 16 + quad * 4 + r;
            if (gm < M)
                Cv[(size_t)gm * 64 + gc] = f2bits(acc[nt][r] + bv);
        }
    }
}

// ---------------------------------------------------------------------------
// Batched transpose+cvt. Optional second job set via (src1b, dstb): blocks
// with z >= 6 process job B (same R1/R2/Nn shape).
// ---------------------------------------------------------------------------
__global__ __launch_bounds__(256)
void transpose_cvt(const float* __restrict__ src1, const float* __restrict__ src2,
                   unsigned short* __restrict__ dst, int R1, int R2, int Nn,
                   const float* __restrict__ src1b, unsigned short* __restrict__ dstb)
{
    __shared__ float tile[32][33];
    const int R = R1 + R2;
    int e = blockIdx.z;
    const float* s1 = src1;
    unsigned short* d = dst;
    if (src1b && e >= 6) { s1 = src1b; d = dstb; e -= 6; }
    s1 += (size_t)e * R1 * Nn;
    const float* s2 = src2 ? src2 + (size_t)e * R2 * Nn : nullptr;
    d += (size_t)e * Nn * R;
    const int r0 = blockIdx.x * 32, n0 = blockIdx.y * 32;
    const int lr = threadIdx.x >> 5, ln = threadIdx.x & 31;
#pragma unroll
    for (int i = 0; i < 4; ++i) {
        int r = r0 + lr + i * 8, n = n0 + ln;
        float v = 0.f;
        if (r < R && n < Nn) v = (r < R1) ? s1[(size_t)r * Nn + n]
                                          : s2[(size_t)(r - R1) * Nn + n];
        tile[lr + i * 8][ln] = v;
    }
    __syncthreads();
#pragma unroll
    for (int i = 0; i < 4; ++i) {
        int n = n0 + lr + i * 8, r = r0 + ln;
        if (n < Nn && r < R) d[(size_t)n * R + r] = f2bits(tile[ln][lr + i * 8]);
    }
}

// merged W2T/W3T/W4T transpose: z selects job, early-exit out-of-range blocks
__global__ __launch_bounds__(256)
void tcvt_mlp_k(const float* __restrict__ W2, const float* __restrict__ W3,
                const float* __restrict__ W4, unsigned short* __restrict__ d2,
                unsigned short* __restrict__ d3, unsigned short* __restrict__ d4)
{
    const int z = blockIdx.z;
    const float* src; unsigned short* dst; int R, Nn, gx, gy;
    if (z == 0)      { src = W2; dst = d2; R = 256;  Nn = 512;  gx = 8;  gy = 16; }
    else if (z == 1) { src = W3; dst = d3; R = 512;  Nn = 1024; gx = 16; gy = 32; }
    else             { src = W4; dst = d4; R = 1024; Nn = 4096; gx = 32; gy = 128; }
    if (blockIdx.x >= (unsigned)gx || blockIdx.y >= (unsigned)gy) return;
    __shared__ float tile[32][33];
    const int r0 = blockIdx.x * 32, n0 = blockIdx.y * 32;
    const int lr = threadIdx.x >> 5, ln = threadIdx.x & 31;
#pragma unroll
    for (int i = 0; i < 4; ++i) {
        int r = r0 + lr + i * 8, n = n0 + ln;
        float v = 0.f;
        if (r < R && n < Nn) v = src[(size_t)r * Nn + n];
        tile[lr + i * 8][ln] = v;
    }
    __syncthreads();
#pragma unroll
    for (int i = 0; i < 4; ++i) {
        int n = n0 + lr + i * 8, r = r0 + ln;
        if (n < Nn && r < R) dst[(size_t)n * R + r] = f2bits(tile[ln][lr + i * 8]);
    }
}

// fused self+neigh weight prep; optional second layer set via z >= 3.
__global__ __launch_bounds__(256)
void fuse_w_k(const float* __restrict__ Ws, const float* __restrict__ Wn,
              unsigned short* __restrict__ dst, int F,
              const float* __restrict__ Wsb, const float* __restrict__ Wnb,
              unsigned short* __restrict__ dstb)
{
    const int PAe[3] = {1, 0, 2}, PBe[3] = {3, 4, 5};
    __shared__ float tile[32][33];
    int p = blockIdx.z;
    const float* ws_ = Ws; const float* wn_ = Wn; unsigned short* db = dst;
    if (Wsb && p >= 3) { ws_ = Wsb; wn_ = Wnb; db = dstb; p -= 3; }
    const int eA = PAe[p], eB = PBe[p];
    const int Kt = 3 * F;
    unsigned short* D = db + (size_t)p * 64 * Kt;
    const int r0 = blockIdx.x * 32;
    const int n0 = blockIdx.y * 32;
    const int lr = threadIdx.x >> 5, ln = threadIdx.x & 31;
    for (int seg = 0; seg < 3; ++seg) {
        __syncthreads();
#pragma unroll
        for (int i = 0; i < 4; ++i) {
            int r = r0 + lr + i * 8, n = n0 + ln;
            float v;
            if (seg == 0)
                v = ws_[((size_t)eA * F + r) * 64 + n] + ws_[((size_t)eB * F + r) * 64 + n];
            else if (seg == 1)
                v = wn_[((size_t)eA * F + r) * 64 + n];
            else
                v = wn_[((size_t)eB * F + r) * 64 + n];
            tile[lr + i * 8][ln] = v;
        }
        __syncthreads();
        const int koff = seg * F;
#pragma unroll
        for (int i = 0; i < 4; ++i) {
            int n = n0 + lr + i * 8, r = r0 + ln;
            D[(size_t)n * Kt + koff + r] = f2bits(tile[ln][lr + i * 8]);
        }
    }
}

// 3 h0 feature matrices -> bf16, batched over z
__global__ __launch_bounds__(256)
void cvt3_k(const float* __restrict__ s0, const float* __restrict__ s1,
            const float* __restrict__ s2, unsigned short* __restrict__ dst)
{
    const int z = blockIdx.z;
    const float* src = z == 0 ? s0 : (z == 1 ? s1 : s2);
    dst += (size_t)z * NNODE * 128;
    int i = blockIdx.x * 256 + threadIdx.x;
    if (i >= 1600000) return;
    float4 v = ((const float4*)src)[i];
    ushort4 w;
    w.x = f2bits(v.x); w.y = f2bits(v.y); w.z = f2bits(v.z); w.w = f2bits(v.w);
    ((ushort4*)dst)[i] = w;
}

// Adj fp32 [4096][4096] -> bf16 strided [4096][4160] (fake tail filled later)
__global__ __launch_bounds__(256)
void cvt_adj_k(const float* __restrict__ src, unsigned short* __restrict__ dst)
{
    int i = blockIdx.x * 256 + threadIdx.x;
    if (i >= 4194304) return;
    int r = i >> 10, c4 = i & 1023;
    float4 v = ((const float4*)src)[i];
    ushort4 w;
    w.x = f2bits(v.x); w.y = f2bits(v.y); w.z = f2bits(v.z); w.w = f2bits(v.w);
    *(ushort4*)(dst + (size_t)r * 4160 + c4 * 4) = w;
}

// ---------------------------------------------------------------------------
// CSR build, atomic-histogram-free.
// ---------------------------------------------------------------------------
__global__ __launch_bounds__(256)
void binit_k(int* __restrict__ bcur, int* __restrict__ dh)
{
    bcur[blockIdx.x * NBKT + threadIdx.x] = threadIdx.x * BCAP;
    if (threadIdx.x < 64) dh[blockIdx.x * 64 + threadIdx.x] = 0;
}

__global__ __launch_bounds__(256)
void bucket_k(const int* __restrict__ edges, int* __restrict__ bcur,
              unsigned* __restrict__ ebuf)
{
    const int r = blockIdx.y;
    const int base = blockIdx.x * 4096;
    const int tid = threadIdx.x;
    __shared__ int lcnt[NBKT];
    __shared__ int lbase[NBKT];
    for (int i = tid; i < NBKT; i += 256) lcnt[i] = 0;
    __syncthreads();
    unsigned ent[16];
    int rnk[16];
#pragma unroll
    for (int i = 0; i < 16; ++i) {
        int e = base + tid + i * 256;
        ent[i] = 0xffffffffu;
        rnk[i] = 0;
        if (e < NEDGE) {
            int src = edges[(size_t)r * 2 * NEDGE + e];
            int dst = edges[(size_t)r * 2 * NEDGE + NEDGE + e];
            ent[i] = ((unsigned)dst << 16) | (unsigned)src;
            rnk[i] = atomicAdd(&lcnt[dst / BWID], 1);
        }
    }
    __syncthreads();
    for (int i = tid; i < NBKT; i += 256)
        lbase[i] = lcnt[i] ? atomicAdd(&bcur[r * NBKT + i], lcnt[i]) : 0;
    __syncthreads();
#pragma unroll
    for (int i = 0; i < 16; ++i)
        if (ent[i] != 0xffffffffu) {
            int b = (int)(ent[i] >> 16) / BWID;
            int pos = lbase[b] + rnk[i];
            if (pos < (b + 1) * BCAP)
                ebuf[(size_t)r * RELEB + pos] = ent[i];
        }
}

__global__ __launch_bounds__(256)
void bscan_k(const int* __restrict__ bcur, int* __restrict__ bbase,
             int* __restrict__ offs)
{
    const int r = blockIdx.x, tid = threadIdx.x;
    const int lane = tid & 63, wv = tid >> 6;
    int v = bcur[r * NBKT + tid] - tid * BCAP;
    if (v > BCAP) v = BCAP;
    int x = v;
#pragma unroll
    for (int off = 1; off < 64; off <<= 1) {
        int t = __shfl_up(x, off);
        if (lane >= off) x += t;
    }
    __shared__ int wsum[4];
    if (lane == 63) wsum[wv] = x;
    __syncthreads();
    int add = 0;
#pragma unroll
    for (int w = 0; w < 4; ++w) if (w < wv) add += wsum[w];
    x += add;
    bbase[r * NBKT + tid] = x - v;
    if (tid == 255) offs[(size_t)r * (NNODE + 1) + NNODE] = x;
}

__global__ __launch_bounds__(256)
void debucket_k(const unsigned* __restrict__ ebuf, const int* __restrict__ bcur,
                const int* __restrict__ bbase, int* __restrict__ offs,
                unsigned short* __restrict__ srcs)
{
    const int r = blockIdx.y, b = blockIdx.x, tid = threadIdx.x;
    const int lo = b * BWID;
    __shared__ unsigned es[BCAP];
    __shared__ unsigned short stage[BCAP];
    __shared__ int lhist[256];
    __shared__ int buf[256];
    __shared__ int lcur[256];
    int cnt = bcur[r * NBKT + b] - b * BCAP;
    if (cnt > BCAP) cnt = BCAP;
    const int base = bbase[r * NBKT + b];
    lhist[tid] = 0;
    __syncthreads();
    for (int j = tid; j < cnt; j += 256) {
        unsigned e = ebuf[(size_t)r * RELEB + (size_t)b * BCAP + j];
        es[j] = e;
        atomicAdd(&lhist[(int)(e >> 16) - lo], 1);
    }
    __syncthreads();
    int v = lhist[tid];
    buf[tid] = v;
    __syncthreads();
    for (int off = 1; off < 256; off <<= 1) {
        int t = (tid >= off) ? buf[tid - off] : 0;
        __syncthreads();
        buf[tid] += t;
        __syncthreads();
    }
    int excl = buf[tid] - v;
    int node = lo + tid;
    if (tid < BWID && node < NNODE) offs[(size_t)r * (NNODE + 1) + node] = base + excl;
    lcur[tid] = excl;
    __syncthreads();
    for (int j = tid; j < cnt; j += 256) {
        unsigned e = es[j];
        int d = (int)(e >> 16) - lo;
        int p = atomicAdd(&lcur[d], 1);
        stage[p] = (unsigned short)(e & 0xffffu);
    }
    __syncthreads();
    for (int j = tid; j < cnt; j += 256)
        srcs[(size_t)r * NEDGE + base + j] = stage[j];
}

// ---------------------------------------------------------------------------
// Degree-order build: counting-sort node ids by degree (64 bins) so gather
// waves process uniform-degree nodes (kills max-of-group divergence).
// ---------------------------------------------------------------------------
__global__ __launch_bounds__(256)
void dhist_k(const int* __restrict__ offs, int* __restrict__ dh)
{
    const int r = blockIdx.y;
    const int n = blockIdx.x * 256 + threadIdx.x;
    __shared__ int h[64];
    if (threadIdx.x < 64) h[threadIdx.x] = 0;
    __syncthreads();
    if (n < NNODE) {
        int d = offs[(size_t)r * (NNODE + 1) + n + 1] - offs[(size_t)r * (NNODE + 1) + n];
        atomicAdd(&h[min(d, 63)], 1);
    }
    __syncthreads();
    if (threadIdx.x < 64 && h[threadIdx.x])
        atomicAdd(&dh[r * 64 + threadIdx.x], h[threadIdx.x]);
}

__global__ __launch_bounds__(64)
void dscan_k(int* __restrict__ dh)   // in-place: counts -> exclusive bases
{
    const int r = blockIdx.x, t = threadIdx.x;
    int v = dh[r * 64 + t];
    int x = v;
#pragma unroll
    for (int off = 1; off < 64; off <<= 1) {
        int u = __shfl_up(x, off);
        if (t >= off) x += u;
    }
    dh[r * 64 + t] = x - v;
}

__global__ __launch_bounds__(256)
void dfill_k(const int* __restrict__ offs, int* __restrict__ dcur,
             unsigned short* __restrict__ order)
{
    const int r = blockIdx.y;
    const int n = blockIdx.x * 256 + threadIdx.x;
    const int tid = threadIdx.x;
    __shared__ int lcnt[64];
    __shared__ int lbase[64];
    if (tid < 64) lcnt[tid] = 0;
    __syncthreads();
    int bin = 0, rnk = 0;
    bool ok = n < NNODE;
    if (ok) {
        int d = offs[(size_t)r * (NNODE + 1) + n + 1] - offs[(size_t)r * (NNODE + 1) + n];
        bin = min(d, 63);
        rnk = atomicAdd(&lcnt[bin], 1);
    }
    __syncthreads();
    if (tid < 64) lbase[tid] = lcnt[tid] ? atomicAdd(&dcur[r * 64 + tid], lcnt[tid]) : 0;
    __syncthreads();
    if (ok) order[(size_t)r * NNODE + lbase[bin] + rnk] = (unsigned short)n;
}

// ---------------------------------------------------------------------------
// Degree-ordered segment-max gathers (packed u16 max on bf16 bits).
// ---------------------------------------------------------------------------
template<int F>
__global__ __launch_bounds__(256)
void gather2_k(const unsigned short* __restrict__ pooled, const int* __restrict__ offs,
               const unsigned short* __restrict__ srcs, const unsigned short* __restrict__ order,
               unsigned short* __restrict__ agg, int e0, int e1)
{
    const int CG = F / 8;
    const int z = blockIdx.z;
    const int e = z ? e1 : e0;
    pooled += (size_t)z * NNODE * F;
    agg    += (size_t)z * NNODE * F;
    offs   += (size_t)e * (NNODE + 1);
    srcs   += (size_t)e * NEDGE;
    order  += (size_t)e * NNODE;
    int idx = blockIdx.x * 256 + threadIdx.x;
    int g = idx / CG, cg = idx % CG;
    if (g >= NNODE) return;
    int n = order[g];
    int beg = offs[n], end = offs[n + 1];
    unsigned m0 = 0, m1 = 0, m2 = 0, m3 = 0;
    int j = beg;
    for (; j + 4 <= end; j += 4) {
        int s0 = srcs[j], s1 = srcs[j + 1], s2 = srcs[j + 2], s3 = srcs[j + 3];
        uint4 v0 = *(const uint4*)(pooled + (size_t)s0 * F + cg * 8);
        uint4 v1 = *(const uint4*)(pooled + (size_t)s1 * F + cg * 8);
        uint4 v2 = *(const uint4*)(pooled + (size_t)s2 * F + cg * 8);
        uint4 v3 = *(const uint4*)(pooled + (size_t)s3 * F + cg * 8);
        m0 = pk_max_u16(m0, pk_max_u16(pk_max_u16(v0.x, v1.x), pk_max_u16(v2.x, v3.x)));
        m1 = pk_max_u16(m1, pk_max_u16(pk_max_u16(v0.y, v1.y), pk_max_u16(v2.y, v3.y)));
        m2 = pk_max_u16(m2, pk_max_u16(pk_max_u16(v0.z, v1.z), pk_max_u16(v2.z, v3.z)));
        m3 = pk_max_u16(m3, pk_max_u16(pk_max_u16(v0.w, v1.w), pk_max_u16(v2.w, v3.w)));
    }
    for (; j < end; ++j) {
        int s = srcs[j];
        uint4 v = *(const uint4*)(pooled + (size_t)s * F + cg * 8);
        m0 = pk_max_u16(m0, v.x);
        m1 = pk_max_u16(m1, v.y);
        m2 = pk_max_u16(m2, v.z);
        m3 = pk_max_u16(m3, v.w);
    }
    uint4 o; o.x = m0; o.y = m1; o.z = m2; o.w = m3;
    *(uint4*)(agg + (size_t)n * F + cg * 8) = o;
}

__global__ __launch_bounds__(256)
void gather6_k(const unsigned short* __restrict__ pooled6, const int* __restrict__ offs,
               const unsigned short* __restrict__ srcs, const unsigned short* __restrict__ order,
               unsigned short* __restrict__ regA, unsigned short* __restrict__ regB)
{
    const int F = 64, CG = 8;
    const int z = blockIdx.z;
    const unsigned short* pooled = pooled6 + (size_t)z * NNODE * F;
    unsigned short* agg = (z < 4) ? regA + (size_t)z * NNODE * F
                                  : regB + (size_t)(z - 4) * NNODE * F;
    offs  += (size_t)z * (NNODE + 1);
    srcs  += (size_t)z * NEDGE;
    order += (size_t)z * NNODE;
    int idx = blockIdx.x * 256 + threadIdx.x;
    int g = idx / CG, cg = idx % CG;
    if (g >= NNODE) return;
    int n = order[g];
    int beg = offs[n], end = offs[n + 1];
    unsigned m0 = 0, m1 = 0, m2 = 0, m3 = 0;
    int j = beg;
    for (; j + 4 <= end; j += 4) {
        int s0 = srcs[j], s1 = srcs[j + 1], s2 = srcs[j + 2], s3 = srcs[j + 3];
        uint4 v0 = *(const uint4*)(pooled + (size_t)s0 * F + cg * 8);
        uint4 v1 = *(const uint4*)(pooled + (size_t)s1 * F + cg * 8);
        uint4 v2 = *(const uint4*)(pooled + (size_t)s2 * F + cg * 8);
        uint4 v3 = *(const uint4*)(pooled + (size_t)s3 * F + cg * 8);
        m0 = pk_max_u16(m0, pk_max_u16(pk_max_u16(v0.x, v1.x), pk_max_u16(v2.x, v3.x)));
        m1 = pk_max_u16(m1, pk_max_u16(pk_max_u16(v0.y, v1.y), pk_max_u16(v2.y, v3.y)));
        m2 = pk_max_u16(m2, pk_max_u16(pk_max_u16(v0.z, v1.z), pk_max_u16(v2.z, v3.z)));
        m3 = pk_max_u16(m3, pk_max_u16(pk_max_u16(v0.w, v1.w), pk_max_u16(v2.w, v3.w)));
    }
    for (; j < end; ++j) {
        int s = srcs[j];
        uint4 v = *(const uint4*)(pooled + (size_t)s * F + cg * 8);
        m0 = pk_max_u16(m0, v.x);
        m1 = pk_max_u16(m1, v.y);
        m2 = pk_max_u16(m2, v.z);
        m3 = pk_max_u16(m3, v.w);
    }
    uint4 o; o.x = m0; o.y = m1; o.z = m2; o.w = m3;
    *(uint4*)(agg + (size_t)n * F + cg * 8) = o;
}

__global__ __launch_bounds__(64)
void fake_k(const unsigned short* __restrict__ mirna, const float* __restrict__ noise,
            const int* __restrict__ t_p, const int* __restrict__ left_p,
            unsigned short* __restrict__ adj_s, float* __restrict__ fake_out)
{
    int r = blockIdx.x, c = threadIdx.x;
    int t = *t_p, left = *left_p;
    int row = left + r;
    float x = bits2f(mirna[(size_t)row * 64 + c]);
    float s = fabsf(x);
#pragma unroll
    for (int off = 32; off > 0; off >>= 1) s += __shfl_down(s, off);
    s = __shfl(s, 0);
    float ab = 1.f;
    for (int i = 0; i <= t; ++i)
        ab *= (1.f - (1e-4f + (0.02f - 1e-4f) * ((float)i / 99.f)));
    float v = sqrtf(ab) * (x / fmaxf(s, 1e-12f)) + sqrtf(1.f - ab) * noise[(size_t)row * 64 + c];
    adj_s[(size_t)r * 4160 + 4096 + c] = f2bits(v);   // fake tail of strided Adj
    fake_out[(size_t)r * 64 + c] = v;
}

// ---------------------------------------------------------------------------
extern "C" void kernel_launch(void* const* d_in, const int* in_sizes, int n_in,
                              void* d_out, int out_size, void* d_ws, size_t ws_size,
                              hipStream_t stream)
{
    const float* h0[3]    = {(const float*)d_in[0], (const float*)d_in[1], (const float*)d_in[2]};
    const float* Wpool[3] = {(const float*)d_in[3], (const float*)d_in[8],  (const float*)d_in[13]};
    const float* bpool[3] = {(const float*)d_in[4], (const float*)d_in[9],  (const float*)d_in[14]};
    const float* bself[3] = {(const float*)d_in[6], (const float*)d_in[11], (const float*)d_in[16]};
    const float* Wself[3] = {(const float*)d_in[5], (const float*)d_in[10], (const float*)d_in[15]};
    const float* Wneigh[3]= {(const float*)d_in[7], (const float*)d_in[12], (const float*)d_in[17]};
    const float* Adj   = (const float*)d_in[18];
    const float* noise = (const float*)d_in[19];
    const float* W1 = (const float*)d_in[20]; const float* b1 = (const float*)d_in[21];
    const float* W2 = (const float*)d_in[22]; const float* b2 = (const float*)d_in[23];
    const float* W3 = (const float*)d_in[24]; const float* b3 = (const float*)d_in[25];
    const float* W4 = (const float*)d_in[26]; const float* b4 = (const float*)d_in[27];
    const int* edges  = (const int*)d_in[28];
    const int* t_p    = (const int*)d_in[29];
    const int* left_p = (const int*)d_in[31];

    // workspace layout (bf16-element offsets); total ~118.4 MB
    unsigned short* ws = (unsigned short*)d_ws;
    const size_t P1 = 0, P2 = 98304, P3 = 122880;
    const size_t FU1 = 147456, FU2 = 245760, FU3 = 294912;   // fused pair weights
    const size_t W1T = 344064, W2T = 1409024, W3T = 1540096, W4T = 2064384;
    const size_t ADJ = 6258688;        // 4096*4160 bf16 (strided, fake tail)
    const size_t POOLED = 23298048;    // 25.6MB region (to HA)
    const size_t HA = 36098048, HB = 45698048;   // 3*50000*64 bf16 each
    int* bcur  = (int*)(ws + 55298048);          // 6*NBKT
    int* bbase = bcur + 6 * NBKT;                // 6*NBKT
    int* offs  = bbase + 6 * NBKT;               // 6*(NNODE+1)
    int* dh    = offs + 6 * (NNODE + 1);         // 6*64 degree bins / cursors
    unsigned short* srcs = (unsigned short*)(dh + 6 * 64);   // 6*NEDGE u16
    unsigned short* order = srcs + (size_t)6 * NEDGE;        // 6*NNODE u16
    unsigned* ebuf = (unsigned*)(ws + POOLED);   // 6*RELEB u32; dead before layer 1
    unsigned short* x1 = ws + POOLED;            // MLP scratch (dead after layer 3)
    unsigned short* x2 = x1 + (size_t)SZ * 256;
    unsigned short* x3 = x2 + (size_t)SZ * 512;
    unsigned short* adj_s = ws + ADJ;
    float* out_fake = (float*)d_out;
    float* out_x    = out_fake + (size_t)SZ * 64;
    // out_x (64MB) as scratch until fake_k:
    unsigned short* hb0 = (unsigned short*)out_x;     // h0 bf16 (38.4MB), layer 1
    unsigned short* agg2_l1 = hb0 + 19200000;         // layer-1 agg2 (25.6MB tail)
    unsigned short* pooled6 = (unsigned short*)out_x; // layers 2/3 pooled (38.4MB)
    unsigned short* aggB6 = pooled6 + 19200000;       // agg slots 4-5 (12.8MB)
    unsigned short* aggA6 = ws + POOLED;              // agg slots 0-3 (25.6MB)
    float* x1p = out_x;                               // MLP1 partials (ZK1*4MB)

    const int SRCr[6] = {0, 1, 0, 2, 2, 1};
    const int PAe[3] = {1, 0, 2}, PBe[3] = {3, 4, 5};   // dst pairs: p -> (eA,eB), dst=p
    dim3 T(256);

    // ---- prep: weight transposes (merged) + conversions ----
    transpose_cvt<<<dim3(4, 4, 6), T, 0, stream>>>(Wpool[0], nullptr, ws + P1, 128, 0, 128,
                                                   nullptr, nullptr);
    transpose_cvt<<<dim3(2, 2, 12), T, 0, stream>>>(Wpool[1], nullptr, ws + P2, 64, 0, 64,
                                                    Wpool[2], ws + P3);
    fuse_w_k<<<dim3(4, 2, 3), T, 0, stream>>>(Wself[0], Wneigh[0], ws + FU1, 128,
                                              nullptr, nullptr, nullptr);
    fuse_w_k<<<dim3(2, 2, 6), T, 0, stream>>>(Wself[1], Wneigh[1], ws + FU2, 64,
                                              Wself[2], Wneigh[2], ws + FU3);
    transpose_cvt<<<dim3(130, 8, 1), T, 0, stream>>>(W1, nullptr, ws + W1T, 4160, 0, 256,
                                                     nullptr, nullptr);
    tcvt_mlp_k<<<dim3(32, 128, 3), T, 0, stream>>>(W2, W3, W4, ws + W2T, ws + W3T, ws + W4T);
    cvt_adj_k<<<16384, T, 0, stream>>>(Adj, adj_s);
    cvt3_k<<<dim3(6250, 1, 3), T, 0, stream>>>(h0[0], h0[1], h0[2], hb0);

    // ---- CSR build + degree ordering ----
    binit_k<<<6, T, 0, stream>>>(bcur, dh);
    bucket_k<<<dim3(123, 6), T, 0, stream>>>(edges, bcur, ebuf);
    bscan_k<<<6, T, 0, stream>>>(bcur, bbase, offs);
    debucket_k<<<dim3(NBKT, 6), T, 0, stream>>>(ebuf, bcur, bbase, offs, srcs);
    dhist_k<<<dim3(196, 6), T, 0, stream>>>(offs, dh);
    dscan_k<<<6, dim3(64), 0, stream>>>(dh);
    dfill_k<<<dim3(196, 6), T, 0, stream>>>(offs, dh, order);

    // ---- layer 1 (hb0 bf16, 128 -> 64), z=2-batched per dst pair ----
    for (int p = 0; p < 3; ++p) {
        const int eA = PAe[p], eB = PBe[p];
        pool2_k<8><<<dim3(1, 782, 2), T, 0, stream>>>(
            hb0 + (size_t)SRCr[eA] * NNODE * 128, hb0 + (size_t)SRCr[eB] * NNODE * 128,
            ws + P1 + (size_t)eA * 16384, ws + P1 + (size_t)eB * 16384,
            bpool[0] + eA * 128, bpool[0] + eB * 128,
            ws + POOLED, NNODE, 128);
        gather2_k<128><<<dim3(3125, 1, 2), T, 0, stream>>>(
            ws + POOLED, offs, srcs, order, agg2_l1, eA, eB);
        mfma_gemm<4><<<dim3(1, 782), T, 0, stream>>>(
            hb0 + (size_t)p * NNODE * 128, agg2_l1, agg2_l1 + (size_t)NNODE * 128,
            ws + FU1 + (size_t)p * 24576, bself[0] + eA * 64, bself[0] + eB * 64,
            ws + HA + (size_t)p * NNODE * 64, NNODE, 64, 128, 128, 128);
    }

    // ---- layers 2,3 (bf16, 64 -> 64), fully z-batched: 3 dispatches/layer ----
    unsigned short* hin = ws + HA;
    unsigned short* hout = ws + HB;
    for (int layer = 1; layer <= 2; ++layer) {
        const unsigned short* pT = ws + (layer == 1 ? P2 : P3);
        const unsigned short* fT = ws + (layer == 1 ? FU2 : FU3);
        pool6_k<<<dim3(1, 782, 6), T, 0, stream>>>(hin, pT, bpool[layer], pooled6, NNODE);
        gather6_k<<<dim3(1563, 1, 6), T, 0, stream>>>(pooled6, offs, srcs, order, aggA6, aggB6);
        fused3_k<<<dim3(1, 782, 3), T, 0, stream>>>(hin, aggA6, aggB6, fT,
                                                    bself[layer], hout, NNODE);
        unsigned short* tmp = hin; hin = hout; hout = tmp;
    }
    // hin == ws+HA holds h3; out_x region dead from here

    fake_k<<<SZ, dim3(64), 0, stream>>>(hin, noise, t_p, left_p, adj_s, out_fake);

    // ---- MLP: PIPE=1 (dbuf) for grid-starved layers, PIPE=0 for MLP4 ----
    gemm128<0, 0, 0, 1, 1><<<dim3(2, 32, ZK1), T, 0, stream>>>(
        adj_s, ws + W1T, b1, x1p, SZ, 256, 4160);
    mlp1_ep_k<<<1024, T, 0, stream>>>(x1p, b1, x1);
    gemm128<1, 0, 0, 0, 1><<<dim3(4, 32),  T, 0, stream>>>(x1, ws + W2T, b2, x2, SZ, 512, 256);
    gemm128<1, 0, 0, 0, 1><<<dim3(8, 32),  T, 0, stream>>>(x2, ws + W3T, b3, x3, SZ, 1024, 512);
    gemm128<0, 1, 1, 0, 0><<<dim3(32, 32), T, 0, stream>>>(x3, ws + W4T, b4, out_x, SZ, 4096, 1024);
}

// Round 12
// 868.671 us; speedup vs baseline: 1.2523x; 1.0149x over previous
//
#include <hip/hip_runtime.h>
#include <hip/hip_bf16.h>

#define NNODE 50000
#define NEDGE 500000
#define SZ    4096
#define NBKT  256   // dst-range buckets per relation
#define BWID  196   // dst nodes per bucket: 256*196 = 50176 >= NNODE
#define BCAP  2560  // fixed bucket capacity (expected load 1953 +- 44; ~13 sigma)
#define RELEB ((size_t)NBKT * BCAP)
#define ZK1   8     // MLP1 split-K factor (65 k-steps -> 9 per z)

typedef __attribute__((ext_vector_type(8))) short bf16x8;
typedef __attribute__((ext_vector_type(4))) float f32x4;

__device__ __forceinline__ float bits2f(unsigned short u) {
    return __uint_as_float(((unsigned)u) << 16);
}
__device__ __forceinline__ unsigned short f2bits(float f) {  // RNE fp32->bf16
    unsigned x = __float_as_uint(f);
    unsigned r = x + 0x7fffu + ((x >> 16) & 1u);
    return (unsigned short)(r >> 16);
}
__device__ __forceinline__ unsigned pk_max_u16(unsigned a, unsigned b) {
    unsigned lo = max(a & 0xffffu, b & 0xffffu);
    unsigned hi = max(a >> 16, b >> 16);
    return lo | (hi << 16);
}
// async global->LDS, 16B per lane; LDS dest = uniform base + lane*16
__device__ __forceinline__ void gl_lds16(const void* g, void* l) {
    __builtin_amdgcn_global_load_lds(
        (const __attribute__((address_space(1))) unsigned int*)g,
        (__attribute__((address_space(3))) unsigned int*)l, 16, 0, 0);
}

// ---------------------------------------------------------------------------
// Big-GEMM: 128x128 tile, BK=64, 4 waves, linear LDS, global_load_lds w16,
// XCD swizzle. PIPE=1: 2-deep LDS double-buffer (grid-starved case);
// PIPE=0: single-buffer 32KB (keeps 4 blocks/CU when grid fills GPU).
// PART=1: split-K over gridDim.z, f32 partials to Cv + z*M*N (no bias/act).
// ---------------------------------------------------------------------------
template<int RELU, int SIG, int OUTF32, int PART, int PIPE>
__global__ __launch_bounds__(256)
void gemm128(const unsigned short* __restrict__ A, const unsigned short* __restrict__ Bt,
             const float* __restrict__ bias, void* __restrict__ Cv, int M, int N, int K)
{
    __shared__ unsigned short As[PIPE + 1][128 * 64];
    __shared__ unsigned short Bs[PIPE + 1][128 * 64];
    const int tid = threadIdx.x;
    const int wave = tid >> 6, lane = tid & 63;
    const int m16 = lane & 15, quad = lane >> 4;
    const int wr = wave >> 1, wc = wave & 1;
    const int nwg = gridDim.x * gridDim.y;
    int bid = blockIdx.y * gridDim.x + blockIdx.x;
    if ((nwg & 7) == 0) { int cpx = nwg >> 3; bid = (bid & 7) * cpx + (bid >> 3); }
    const int bx = bid % gridDim.x, by = bid / gridDim.x;
    const int row0 = by * 128, col0 = bx * 128;
    const int lrow = lane >> 3, lcol = (lane & 7) * 8;

    f32x4 acc[4][4] = {};

    int k0beg = 0, k0end = K;
    if (PART) {
        const int per = ((K >> 6) + gridDim.z - 1) / gridDim.z;
        k0beg = blockIdx.z * per * 64;
        k0end = min(K, k0beg + per * 64);
    }
    const int nt = (k0end - k0beg) >> 6;

    auto STAGE = [&](int b, int k0) {
#pragma unroll
        for (int i = 0; i < 4; ++i) {
            int chunk = wave * 4 + i;
            int row = chunk * 8 + lrow;
            gl_lds16(A  + (size_t)(row0 + row) * K + k0 + lcol, &As[b][chunk * 512]);
            gl_lds16(Bt + (size_t)(col0 + row) * K + k0 + lcol, &Bs[b][chunk * 512]);
        }
    };
    auto COMPUTE = [&](int b) {
#pragma unroll
        for (int ks = 0; ks < 2; ++ks) {
            bf16x8 a[4], bb[4];
#pragma unroll
            for (int mt = 0; mt < 4; ++mt)
                a[mt] = *(const bf16x8*)&As[b][(wr * 64 + mt * 16 + m16) * 64 + ks * 32 + quad * 8];
#pragma unroll
            for (int nt2 = 0; nt2 < 4; ++nt2)
                bb[nt2] = *(const bf16x8*)&Bs[b][(wc * 64 + nt2 * 16 + m16) * 64 + ks * 32 + quad * 8];
#pragma unroll
            for (int mt = 0; mt < 4; ++mt)
#pragma unroll
                for (int nt2 = 0; nt2 < 4; ++nt2)
                    acc[mt][nt2] = __builtin_amdgcn_mfma_f32_16x16x32_bf16(a[mt], bb[nt2], acc[mt][nt2], 0, 0, 0);
        }
    };

    if (PIPE) {
        STAGE(0, k0beg);
        __syncthreads();
        int cur = 0;
        for (int t = 0; t < nt; ++t) {
            if (t + 1 < nt) STAGE(cur ^ 1, k0beg + (t + 1) * 64);
            COMPUTE(cur);
            __syncthreads();
            cur ^= 1;
        }
    } else {
        for (int t = 0; t < nt; ++t) {
            STAGE(0, k0beg + t * 64);
            __syncthreads();
            COMPUTE(0);
            __syncthreads();
        }
    }

    if (PART) {
        float* P = (float*)Cv + (size_t)blockIdx.z * M * N;
#pragma unroll
        for (int mt = 0; mt < 4; ++mt)
#pragma unroll
            for (int nt2 = 0; nt2 < 4; ++nt2) {
                int gc = col0 + wc * 64 + nt2 * 16 + m16;
#pragma unroll
                for (int r = 0; r < 4; ++r) {
                    int gm = row0 + wr * 64 + mt * 16 + quad * 4 + r;
                    P[(size_t)gm * N + gc] = acc[mt][nt2][r];
                }
            }
        return;
    }

#pragma unroll
    for (int mt = 0; mt < 4; ++mt) {
#pragma unroll
        for (int nt2 = 0; nt2 < 4; ++nt2) {
            int gc = col0 + wc * 64 + nt2 * 16 + m16;
            float bv = bias[gc];
#pragma unroll
            for (int r = 0; r < 4; ++r) {
                int gm = row0 + wr * 64 + mt * 16 + quad * 4 + r;
                size_t idx = (size_t)gm * N + gc;
                float v = acc[mt][nt2][r] + bv;
                if (RELU) v = fmaxf(v, 0.f);
                if (SIG)  v = 1.f / (1.f + __expf(-v));
                if (OUTF32) ((float*)Cv)[idx] = v;
                else        ((unsigned short*)Cv)[idx] = f2bits(v);
            }
        }
    }
}

// split-K reduce + bias + relu + bf16 cvt for MLP layer 1 (ZK1 partials)
__global__ __launch_bounds__(256)
void mlp1_ep_k(const float* __restrict__ p, const float* __restrict__ b1,
               unsigned short* __restrict__ x1)
{
    const size_t MN = (size_t)SZ * 256;
    int i = blockIdx.x * 256 + threadIdx.x;
    if (i >= (int)(MN / 4)) return;
    float4 s = ((const float4*)p)[i];
#pragma unroll
    for (int z = 1; z < ZK1; ++z) {
        float4 a = ((const float4*)(p + (size_t)z * MN))[i];
        s.x += a.x; s.y += a.y; s.z += a.z; s.w += a.w;
    }
    int base = i * 4;
    ushort4 o;
    o.x = f2bits(fmaxf(s.x + b1[(base + 0) & 255], 0.f));
    o.y = f2bits(fmaxf(s.y + b1[(base + 1) & 255], 0.f));
    o.z = f2bits(fmaxf(s.z + b1[(base + 2) & 255], 0.f));
    o.w = f2bits(fmaxf(s.w + b1[(base + 3) & 255], 0.f));
    ((ushort4*)x1)[i] = o;
}

// ---------------------------------------------------------------------------
// Paired pool GEMM (layer 1): z = 0/1 selects (A, Bt, bias); out slot z*M*N.
// ---------------------------------------------------------------------------
template<int NT>
__global__ __launch_bounds__(256)
void pool2_k(const unsigned short* __restrict__ A0, const unsigned short* __restrict__ A1,
             const unsigned short* __restrict__ Bt0, const unsigned short* __restrict__ Bt1,
             const float* __restrict__ b0, const float* __restrict__ b1,
             unsigned short* __restrict__ out, int M, int K)
{
    __shared__ unsigned short As[64][72];
    __shared__ unsigned short Bs[NT * 16][72];
    const int z = blockIdx.z;
    const unsigned short* A = z ? A1 : A0;
    const unsigned short* Bt = z ? Bt1 : Bt0;
    const float* bias = z ? b1 : b0;
    const int N = NT * 16;
    unsigned short* Cv = out + (size_t)z * M * N;

    const int tid = threadIdx.x;
    const int wave = tid >> 6, lane = tid & 63;
    const int m16 = lane & 15, quad = lane >> 4;
    const int row0 = blockIdx.y * 64, col0 = blockIdx.x * N;

    f32x4 acc[NT] = {};

    for (int k0 = 0; k0 < K; k0 += 64) {
#pragma unroll
        for (int it = 0; it < 2; ++it) {
            int u = tid + it * 256;
            int m = u >> 3, c = (u & 7) * 8;
            int gm = row0 + m;
            uint4 v = make_uint4(0u, 0u, 0u, 0u);
            if (gm < M) v = *(const uint4*)(A + (size_t)gm * K + k0 + c);
            *(uint4*)&As[m][c] = v;
        }
#pragma unroll
        for (int it = 0; it < NT / 2; ++it) {
            int u = tid + it * 256;
            int n = u >> 3, c = (u & 7) * 8;
            uint4 v = *(const uint4*)(Bt + (size_t)(col0 + n) * K + k0 + c);
            *(uint4*)&Bs[n][c] = v;
        }
        __syncthreads();
#pragma unroll
        for (int ks = 0; ks < 2; ++ks) {
            bf16x8 a = *(const bf16x8*)&As[wave * 16 + m16][ks * 32 + quad * 8];
#pragma unroll
            for (int nt = 0; nt < NT; ++nt) {
                bf16x8 b = *(const bf16x8*)&Bs[nt * 16 + m16][ks * 32 + quad * 8];
                acc[nt] = __builtin_amdgcn_mfma_f32_16x16x32_bf16(a, b, acc[nt], 0, 0, 0);
            }
        }
        __syncthreads();
    }

#pragma unroll
    for (int nt = 0; nt < NT; ++nt) {
        int gc = col0 + nt * 16 + m16;
        float bv = bias[gc];
#pragma unroll
        for (int r = 0; r < 4; ++r) {
            int gm = row0 + wave * 16 + quad * 4 + r;
            if (gm < M)
                Cv[(size_t)gm * N + gc] = f2bits(fmaxf(acc[nt][r] + bv, 0.f));
        }
    }
}

// ---------------------------------------------------------------------------
// All-relation pool GEMM (layers 2/3): z = relation 0..5.
// ---------------------------------------------------------------------------
__global__ __launch_bounds__(256)
void pool6_k(const unsigned short* __restrict__ hin, const unsigned short* __restrict__ pT,
             const float* __restrict__ bp, unsigned short* __restrict__ pooled6, int M)
{
    const int SRCr[6] = {0, 1, 0, 2, 2, 1};
    __shared__ unsigned short As[64][72];
    __shared__ unsigned short Bs[64][72];
    const int z = blockIdx.z;
    const unsigned short* A = hin + (size_t)SRCr[z] * M * 64;
    const unsigned short* Bt = pT + (size_t)z * 4096;
    const float* bias = bp + z * 64;
    unsigned short* Cv = pooled6 + (size_t)z * M * 64;

    const int tid = threadIdx.x;
    const int wave = tid >> 6, lane = tid & 63;
    const int m16 = lane & 15, quad = lane >> 4;
    const int row0 = blockIdx.y * 64;

    f32x4 acc[4] = {};

    {
#pragma unroll
        for (int it = 0; it < 2; ++it) {
            int u = tid + it * 256;
            int m = u >> 3, c = (u & 7) * 8;
            int gm = row0 + m;
            uint4 v = make_uint4(0u, 0u, 0u, 0u);
            if (gm < M) v = *(const uint4*)(A + (size_t)gm * 64 + c);
            *(uint4*)&As[m][c] = v;
        }
#pragma unroll
        for (int it = 0; it < 2; ++it) {
            int u = tid + it * 256;
            int n = u >> 3, c = (u & 7) * 8;
            uint4 v = *(const uint4*)(Bt + (size_t)n * 64 + c);
            *(uint4*)&Bs[n][c] = v;
        }
        __syncthreads();
#pragma unroll
        for (int ks = 0; ks < 2; ++ks) {
            bf16x8 a = *(const bf16x8*)&As[wave * 16 + m16][ks * 32 + quad * 8];
#pragma unroll
            for (int nt = 0; nt < 4; ++nt) {
                bf16x8 b = *(const bf16x8*)&Bs[nt * 16 + m16][ks * 32 + quad * 8];
                acc[nt] = __builtin_amdgcn_mfma_f32_16x16x32_bf16(a, b, acc[nt], 0, 0, 0);
            }
        }
    }

#pragma unroll
    for (int nt = 0; nt < 4; ++nt) {
        int gc = nt * 16 + m16;
        float bv = bias[gc];
#pragma unroll
        for (int r = 0; r < 4; ++r) {
            int gm = row0 + wave * 16 + quad * 4 + r;
            if (gm < M)
                Cv[(size_t)gm * 64 + gc] = f2bits(fmaxf(acc[nt][r] + bv, 0.f));
        }
    }
}

// ---------------------------------------------------------------------------
// Fused dst-pair GEMM (layer 1 pair version).
// ---------------------------------------------------------------------------
template<int NT>
__global__ __launch_bounds__(256)
void mfma_gemm(const unsigned short* __restrict__ A1, const unsigned short* __restrict__ A2,
               const unsigned short* __restrict__ A3,
               const unsigned short* __restrict__ Bt, const float* __restrict__ bias,
               const float* __restrict__ bias2,
               unsigned short* __restrict__ Cv, int M, int N, int Ka, int Kb, int Kc)
{
    __shared__ unsigned short As[64][72];
    __shared__ unsigned short Bs[NT * 16][72];
    const int tid = threadIdx.x;
    const int wave = tid >> 6, lane = tid & 63;
    const int m16 = lane & 15, quad = lane >> 4;
    const int row0 = blockIdx.y * 64, col0 = blockIdx.x * (NT * 16);
    const int K = Ka + Kb + Kc;

    f32x4 acc[NT] = {};

    for (int k0 = 0; k0 < K; k0 += 64) {
        const int seg = (k0 >= Ka + Kb) ? 2 : ((k0 >= Ka) ? 1 : 0);
        const unsigned short* src = seg == 2 ? A3 : (seg == 1 ? A2 : A1);
        const int ld = seg == 2 ? Kc : (seg == 1 ? Kb : Ka);
        const int kb = k0 - (seg == 2 ? Ka + Kb : (seg == 1 ? Ka : 0));
#pragma unroll
        for (int it = 0; it < 2; ++it) {
            int u = tid + it * 256;
            int m = u >> 3, c = (u & 7) * 8;
            int gm = row0 + m;
            uint4 v = make_uint4(0u, 0u, 0u, 0u);
            if (gm < M) v = *(const uint4*)(src + (size_t)gm * ld + kb + c);
            *(uint4*)&As[m][c] = v;
        }
#pragma unroll
        for (int it = 0; it < NT / 2; ++it) {
            int u = tid + it * 256;
            int n = u >> 3, c = (u & 7) * 8;
            uint4 v = *(const uint4*)(Bt + (size_t)(col0 + n) * K + k0 + c);
            *(uint4*)&Bs[n][c] = v;
        }
        __syncthreads();
#pragma unroll
        for (int ks = 0; ks < 2; ++ks) {
            bf16x8 a = *(const bf16x8*)&As[wave * 16 + m16][ks * 32 + quad * 8];
#pragma unroll
            for (int nt = 0; nt < NT; ++nt) {
                bf16x8 b = *(const bf16x8*)&Bs[nt * 16 + m16][ks * 32 + quad * 8];
                acc[nt] = __builtin_amdgcn_mfma_f32_16x16x32_bf16(a, b, acc[nt], 0, 0, 0);
            }
        }
        __syncthreads();
    }

#pragma unroll
    for (int nt = 0; nt < NT; ++nt) {
        int gc = col0 + nt * 16 + m16;
        float bv = bias[gc] + bias2[gc];
#pragma unroll
        for (int r = 0; r < 4; ++r) {
            int gm = row0 + wave * 16 + quad * 4 + r;
            if (gm < M)
                Cv[(size_t)gm * N + gc] = f2bits(acc[nt][r] + bv);
        }
    }
}

// ---------------------------------------------------------------------------
// All-pairs fused GEMM (layers 2/3): z = dst pair 0..2, K = 192.
// ---------------------------------------------------------------------------
__global__ __launch_bounds__(256)
void fused3_k(const unsigned short* __restrict__ hin,
              const unsigned short* __restrict__ regA, const unsigned short* __restrict__ regB,
              const unsigned short* __restrict__ fT, const float* __restrict__ bs,
              unsigned short* __restrict__ hout, int M)
{
    const int PAe[3] = {1, 0, 2}, PBe[3] = {3, 4, 5};
    __shared__ unsigned short As[64][72];
    __shared__ unsigned short Bs[64][72];
    const int z = blockIdx.z;
    const int eA = PAe[z], eB = PBe[z];
    const unsigned short* A1 = hin + (size_t)z * M * 64;
    const unsigned short* A2 = (eA < 4) ? regA + (size_t)eA * M * 64 : regB + (size_t)(eA - 4) * M * 64;
    const unsigned short* A3 = (eB < 4) ? regA + (size_t)eB * M * 64 : regB + (size_t)(eB - 4) * M * 64;
    const unsigned short* Bt = fT + (size_t)z * 12288;
    const float* bias = bs + eA * 64;
    const float* bias2 = bs + eB * 64;
    unsigned short* Cv = hout + (size_t)z * M * 64;

    const int tid = threadIdx.x;
    const int wave = tid >> 6, lane = tid & 63;
    const int m16 = lane & 15, quad = lane >> 4;
    const int row0 = blockIdx.y * 64;

    f32x4 acc[4] = {};

#pragma unroll
    for (int seg = 0; seg < 3; ++seg) {
        const unsigned short* src = seg == 2 ? A3 : (seg == 1 ? A2 : A1);
        const int k0 = seg * 64;
#pragma unroll
        for (int it = 0; it < 2; ++it) {
            int u = tid + it * 256;
            int m = u >> 3, c = (u & 7) * 8;
            int gm = row0 + m;
            uint4 v = make_uint4(0u, 0u, 0u, 0u);
            if (gm < M) v = *(const uint4*)(src + (size_t)gm * 64 + c);
            *(uint4*)&As[m][c] = v;
        }
#pragma unroll
        for (int it = 0; it < 2; ++it) {
            int u = tid + it * 256;
            int n = u >> 3, c = (u & 7) * 8;
            uint4 v = *(const uint4*)(Bt + (size_t)n * 192 + k0 + c);
            *(uint4*)&Bs[n][c] = v;
        }
        __syncthreads();
#pragma unroll
        for (int ks = 0; ks < 2; ++ks) {
            bf16x8 a = *(const bf16x8*)&As[wave * 16 + m16][ks * 32 + quad * 8];
#pragma unroll
            for (int nt = 0; nt < 4; ++nt) {
                bf16x8 b = *(const bf16x8*)&Bs[nt * 16 + m16][ks * 32 + quad * 8];
                acc[nt] = __builtin_amdgcn_mfma_f32_16x16x32_bf16(a, b, acc[nt], 0, 0, 0);
            }
        }
        __syncthreads();
    }

#pragma unroll
    for (int nt = 0; nt < 4; ++nt) {
        int gc = nt * 16 + m16;
        float bv = bias[gc] + bias2[gc];
#pragma unroll
        for (int r = 0; r < 4; ++r) {
            int gm = row0 + wave * 16 + quad * 4 + r;
            if (gm < M)
                Cv[(size_t)gm * 64 + gc] = f2bits(acc[nt][r] + bv);
        }
    }
}

// ---------------------------------------------------------------------------
// Batched transpose+cvt. Optional second job set via (src1b, dstb): blocks
// with z >= 6 process job B (same R1/R2/Nn shape).
// ---------------------------------------------------------------------------
__global__ __launch_bounds__(256)
void transpose_cvt(const float* __restrict__ src1, const float* __restrict__ src2,
                   unsigned short* __restrict__ dst, int R1, int R2, int Nn,
                   const float* __restrict__ src1b, unsigned short* __restrict__ dstb)
{
    __shared__ float tile[32][33];
    const int R = R1 + R2;
    int e = blockIdx.z;
    const float* s1 = src1;
    unsigned short* d = dst;
    if (src1b && e >= 6) { s1 = src1b; d = dstb; e -= 6; }
    s1 += (size_t)e * R1 * Nn;
    const float* s2 = src2 ? src2 + (size_t)e * R2 * Nn : nullptr;
    d += (size_t)e * Nn * R;
    const int r0 = blockIdx.x * 32, n0 = blockIdx.y * 32;
    const int lr = threadIdx.x >> 5, ln = threadIdx.x & 31;
#pragma unroll
    for (int i = 0; i < 4; ++i) {
        int r = r0 + lr + i * 8, n = n0 + ln;
        float v = 0.f;
        if (r < R && n < Nn) v = (r < R1) ? s1[(size_t)r * Nn + n]
                                          : s2[(size_t)(r - R1) * Nn + n];
        tile[lr + i * 8][ln] = v;
    }
    __syncthreads();
#pragma unroll
    for (int i = 0; i < 4; ++i) {
        int n = n0 + lr + i * 8, r = r0 + ln;
        if (n < Nn && r < R) d[(size_t)n * R + r] = f2bits(tile[ln][lr + i * 8]);
    }
}

// merged W2T/W3T/W4T transpose: z selects job, early-exit out-of-range blocks
__global__ __launch_bounds__(256)
void tcvt_mlp_k(const float* __restrict__ W2, const float* __restrict__ W3,
                const float* __restrict__ W4, unsigned short* __restrict__ d2,
                unsigned short* __restrict__ d3, unsigned short* __restrict__ d4)
{
    const int z = blockIdx.z;
    const float* src; unsigned short* dst; int R, Nn, gx, gy;
    if (z == 0)      { src = W2; dst = d2; R = 256;  Nn = 512;  gx = 8;  gy = 16; }
    else if (z == 1) { src = W3; dst = d3; R = 512;  Nn = 1024; gx = 16; gy = 32; }
    else             { src = W4; dst = d4; R = 1024; Nn = 4096; gx = 32; gy = 128; }
    if (blockIdx.x >= (unsigned)gx || blockIdx.y >= (unsigned)gy) return;
    __shared__ float tile[32][33];
    const int r0 = blockIdx.x * 32, n0 = blockIdx.y * 32;
    const int lr = threadIdx.x >> 5, ln = threadIdx.x & 31;
#pragma unroll
    for (int i = 0; i < 4; ++i) {
        int r = r0 + lr + i * 8, n = n0 + ln;
        float v = 0.f;
        if (r < R && n < Nn) v = src[(size_t)r * Nn + n];
        tile[lr + i * 8][ln] = v;
    }
    __syncthreads();
#pragma unroll
    for (int i = 0; i < 4; ++i) {
        int n = n0 + lr + i * 8, r = r0 + ln;
        if (n < Nn && r < R) dst[(size_t)n * R + r] = f2bits(tile[ln][lr + i * 8]);
    }
}

// fused self+neigh weight prep; optional second layer set via z >= 3.
__global__ __launch_bounds__(256)
void fuse_w_k(const float* __restrict__ Ws, const float* __restrict__ Wn,
              unsigned short* __restrict__ dst, int F,
              const float* __restrict__ Wsb, const float* __restrict__ Wnb,
              unsigned short* __restrict__ dstb)
{
    const int PAe[3] = {1, 0, 2}, PBe[3] = {3, 4, 5};
    __shared__ float tile[32][33];
    int p = blockIdx.z;
    const float* ws_ = Ws; const float* wn_ = Wn; unsigned short* db = dst;
    if (Wsb && p >= 3) { ws_ = Wsb; wn_ = Wnb; db = dstb; p -= 3; }
    const int eA = PAe[p], eB = PBe[p];
    const int Kt = 3 * F;
    unsigned short* D = db + (size_t)p * 64 * Kt;
    const int r0 = blockIdx.x * 32;
    const int n0 = blockIdx.y * 32;
    const int lr = threadIdx.x >> 5, ln = threadIdx.x & 31;
    for (int seg = 0; seg < 3; ++seg) {
        __syncthreads();
#pragma unroll
        for (int i = 0; i < 4; ++i) {
            int r = r0 + lr + i * 8, n = n0 + ln;
            float v;
            if (seg == 0)
                v = ws_[((size_t)eA * F + r) * 64 + n] + ws_[((size_t)eB * F + r) * 64 + n];
            else if (seg == 1)
                v = wn_[((size_t)eA * F + r) * 64 + n];
            else
                v = wn_[((size_t)eB * F + r) * 64 + n];
            tile[lr + i * 8][ln] = v;
        }
        __syncthreads();
        const int koff = seg * F;
#pragma unroll
        for (int i = 0; i < 4; ++i) {
            int n = n0 + lr + i * 8, r = r0 + ln;
            D[(size_t)n * Kt + koff + r] = f2bits(tile[ln][lr + i * 8]);
        }
    }
}

// 3 h0 feature matrices -> bf16, batched over z
__global__ __launch_bounds__(256)
void cvt3_k(const float* __restrict__ s0, const float* __restrict__ s1,
            const float* __restrict__ s2, unsigned short* __restrict__ dst)
{
    const int z = blockIdx.z;
    const float* src = z == 0 ? s0 : (z == 1 ? s1 : s2);
    dst += (size_t)z * NNODE * 128;
    int i = blockIdx.x * 256 + threadIdx.x;
    if (i >= 1600000) return;
    float4 v = ((const float4*)src)[i];
    ushort4 w;
    w.x = f2bits(v.x); w.y = f2bits(v.y); w.z = f2bits(v.z); w.w = f2bits(v.w);
    ((ushort4*)dst)[i] = w;
}

// Adj fp32 [4096][4096] -> bf16 strided [4096][4160] (fake tail filled later)
__global__ __launch_bounds__(256)
void cvt_adj_k(const float* __restrict__ src, unsigned short* __restrict__ dst)
{
    int i = blockIdx.x * 256 + threadIdx.x;
    if (i >= 4194304) return;
    int r = i >> 10, c4 = i & 1023;
    float4 v = ((const float4*)src)[i];
    ushort4 w;
    w.x = f2bits(v.x); w.y = f2bits(v.y); w.z = f2bits(v.z); w.w = f2bits(v.w);
    *(ushort4*)(dst + (size_t)r * 4160 + c4 * 4) = w;
}

// ---------------------------------------------------------------------------
// CSR build, atomic-histogram-free.
// ---------------------------------------------------------------------------
__global__ __launch_bounds__(256)
void binit_k(int* __restrict__ bcur)
{
    bcur[blockIdx.x * NBKT + threadIdx.x] = threadIdx.x * BCAP;
}

__global__ __launch_bounds__(256)
void bucket_k(const int* __restrict__ edges, int* __restrict__ bcur,
              unsigned* __restrict__ ebuf)
{
    const int r = blockIdx.y;
    const int base = blockIdx.x * 4096;
    const int tid = threadIdx.x;
    __shared__ int lcnt[NBKT];
    __shared__ int lbase[NBKT];
    for (int i = tid; i < NBKT; i += 256) lcnt[i] = 0;
    __syncthreads();
    unsigned ent[16];
    int rnk[16];
#pragma unroll
    for (int i = 0; i < 16; ++i) {
        int e = base + tid + i * 256;
        ent[i] = 0xffffffffu;
        rnk[i] = 0;
        if (e < NEDGE) {
            int src = edges[(size_t)r * 2 * NEDGE + e];
            int dst = edges[(size_t)r * 2 * NEDGE + NEDGE + e];
            ent[i] = ((unsigned)dst << 16) | (unsigned)src;
            rnk[i] = atomicAdd(&lcnt[dst / BWID], 1);
        }
    }
    __syncthreads();
    for (int i = tid; i < NBKT; i += 256)
        lbase[i] = lcnt[i] ? atomicAdd(&bcur[r * NBKT + i], lcnt[i]) : 0;
    __syncthreads();
#pragma unroll
    for (int i = 0; i < 16; ++i)
        if (ent[i] != 0xffffffffu) {
            int b = (int)(ent[i] >> 16) / BWID;
            int pos = lbase[b] + rnk[i];
            if (pos < (b + 1) * BCAP)
                ebuf[(size_t)r * RELEB + pos] = ent[i];
        }
}

__global__ __launch_bounds__(256)
void bscan_k(const int* __restrict__ bcur, int* __restrict__ bbase,
             int* __restrict__ offs)
{
    const int r = blockIdx.x, tid = threadIdx.x;
    const int lane = tid & 63, wv = tid >> 6;
    int v = bcur[r * NBKT + tid] - tid * BCAP;
    if (v > BCAP) v = BCAP;
    int x = v;
#pragma unroll
    for (int off = 1; off < 64; off <<= 1) {
        int t = __shfl_up(x, off);
        if (lane >= off) x += t;
    }
    __shared__ int wsum[4];
    if (lane == 63) wsum[wv] = x;
    __syncthreads();
    int add = 0;
#pragma unroll
    for (int w = 0; w < 4; ++w) if (w < wv) add += wsum[w];
    x += add;
    bbase[r * NBKT + tid] = x - v;
    if (tid == 255) offs[(size_t)r * (NNODE + 1) + NNODE] = x;
}

__global__ __launch_bounds__(256)
void debucket_k(const unsigned* __restrict__ ebuf, const int* __restrict__ bcur,
                const int* __restrict__ bbase, int* __restrict__ offs,
                unsigned short* __restrict__ srcs)
{
    const int r = blockIdx.y, b = blockIdx.x, tid = threadIdx.x;
    const int lo = b * BWID;
    __shared__ unsigned es[BCAP];
    __shared__ unsigned short stage[BCAP];
    __shared__ int lhist[256];
    __shared__ int buf[256];
    __shared__ int lcur[256];
    int cnt = bcur[r * NBKT + b] - b * BCAP;
    if (cnt > BCAP) cnt = BCAP;
    const int base = bbase[r * NBKT + b];
    lhist[tid] = 0;
    __syncthreads();
    for (int j = tid; j < cnt; j += 256) {
        unsigned e = ebuf[(size_t)r * RELEB + (size_t)b * BCAP + j];
        es[j] = e;
        atomicAdd(&lhist[(int)(e >> 16) - lo], 1);
    }
    __syncthreads();
    int v = lhist[tid];
    buf[tid] = v;
    __syncthreads();
    for (int off = 1; off < 256; off <<= 1) {
        int t = (tid >= off) ? buf[tid - off] : 0;
        __syncthreads();
        buf[tid] += t;
        __syncthreads();
    }
    int excl = buf[tid] - v;
    int node = lo + tid;
    if (tid < BWID && node < NNODE) offs[(size_t)r * (NNODE + 1) + node] = base + excl;
    lcur[tid] = excl;
    __syncthreads();
    for (int j = tid; j < cnt; j += 256) {
        unsigned e = es[j];
        int d = (int)(e >> 16) - lo;
        int p = atomicAdd(&lcur[d], 1);
        stage[p] = (unsigned short)(e & 0xffffu);
    }
    __syncthreads();
    for (int j = tid; j < cnt; j += 256)
        srcs[(size_t)r * NEDGE + base + j] = stage[j];
}

// ---------------------------------------------------------------------------
// Segment-max gathers (packed u16 max on bf16 bits; relu => all >= 0).
// gather2 (layer 1, F=128): 8-wide unrolled MLP; gather6 (layers 2/3): 4-wide.
// ---------------------------------------------------------------------------
template<int F>
__global__ __launch_bounds__(256)
void gather2_k(const unsigned short* __restrict__ pooled, const int* __restrict__ offs,
               const unsigned short* __restrict__ srcs, unsigned short* __restrict__ agg,
               int e0, int e1)
{
    const int CG = F / 8;
    const int z = blockIdx.z;
    const int e = z ? e1 : e0;
    pooled += (size_t)z * NNODE * F;
    agg    += (size_t)z * NNODE * F;
    offs   += (size_t)e * (NNODE + 1);
    srcs   += (size_t)e * NEDGE;
    int idx = blockIdx.x * 256 + threadIdx.x;
    int n = idx / CG, cg = idx % CG;
    if (n >= NNODE) return;
    int beg = offs[n], end = offs[n + 1];
    unsigned m0 = 0, m1 = 0, m2 = 0, m3 = 0;
    int j = beg;
    for (; j + 8 <= end; j += 8) {
        uint4 v0 = *(const uint4*)(pooled + (size_t)srcs[j + 0] * F + cg * 8);
        uint4 v1 = *(const uint4*)(pooled + (size_t)srcs[j + 1] * F + cg * 8);
        uint4 v2 = *(const uint4*)(pooled + (size_t)srcs[j + 2] * F + cg * 8);
        uint4 v3 = *(const uint4*)(pooled + (size_t)srcs[j + 3] * F + cg * 8);
        uint4 v4 = *(const uint4*)(pooled + (size_t)srcs[j + 4] * F + cg * 8);
        uint4 v5 = *(const uint4*)(pooled + (size_t)srcs[j + 5] * F + cg * 8);
        uint4 v6 = *(const uint4*)(pooled + (size_t)srcs[j + 6] * F + cg * 8);
        uint4 v7 = *(const uint4*)(pooled + (size_t)srcs[j + 7] * F + cg * 8);
        m0 = pk_max_u16(m0, pk_max_u16(pk_max_u16(pk_max_u16(v0.x, v1.x), pk_max_u16(v2.x, v3.x)),
                                       pk_max_u16(pk_max_u16(v4.x, v5.x), pk_max_u16(v6.x, v7.x))));
        m1 = pk_max_u16(m1, pk_max_u16(pk_max_u16(pk_max_u16(v0.y, v1.y), pk_max_u16(v2.y, v3.y)),
                                       pk_max_u16(pk_max_u16(v4.y, v5.y), pk_max_u16(v6.y, v7.y))));
        m2 = pk_max_u16(m2, pk_max_u16(pk_max_u16(pk_max_u16(v0.z, v1.z), pk_max_u16(v2.z, v3.z)),
                                       pk_max_u16(pk_max_u16(v4.z, v5.z), pk_max_u16(v6.z, v7.z))));
        m3 = pk_max_u16(m3, pk_max_u16(pk_max_u16(pk_max_u16(v0.w, v1.w), pk_max_u16(v2.w, v3.w)),
                                       pk_max_u16(pk_max_u16(v4.w, v5.w), pk_max_u16(v6.w, v7.w))));
    }
    for (; j < end; ++j) {
        int s = srcs[j];
        uint4 v = *(const uint4*)(pooled + (size_t)s * F + cg * 8);
        m0 = pk_max_u16(m0, v.x);
        m1 = pk_max_u16(m1, v.y);
        m2 = pk_max_u16(m2, v.z);
        m3 = pk_max_u16(m3, v.w);
    }
    uint4 o; o.x = m0; o.y = m1; o.z = m2; o.w = m3;
    *(uint4*)(agg + (size_t)n * F + cg * 8) = o;
}

__global__ __launch_bounds__(256)
void gather6_k(const unsigned short* __restrict__ pooled6, const int* __restrict__ offs,
               const unsigned short* __restrict__ srcs,
               unsigned short* __restrict__ regA, unsigned short* __restrict__ regB)
{
    const int F = 64, CG = 8;
    const int z = blockIdx.z;
    const unsigned short* pooled = pooled6 + (size_t)z * NNODE * F;
    unsigned short* agg = (z < 4) ? regA + (size_t)z * NNODE * F
                                  : regB + (size_t)(z - 4) * NNODE * F;
    offs += (size_t)z * (NNODE + 1);
    srcs += (size_t)z * NEDGE;
    int idx = blockIdx.x * 256 + threadIdx.x;
    int n = idx / CG, cg = idx % CG;
    if (n >= NNODE) return;
    int beg = offs[n], end = offs[n + 1];
    unsigned m0 = 0, m1 = 0, m2 = 0, m3 = 0;
    int j = beg;
    for (; j + 4 <= end; j += 4) {
        int s0 = srcs[j], s1 = srcs[j + 1], s2 = srcs[j + 2], s3 = srcs[j + 3];
        uint4 v0 = *(const uint4*)(pooled + (size_t)s0 * F + cg * 8);
        uint4 v1 = *(const uint4*)(pooled + (size_t)s1 * F + cg * 8);
        uint4 v2 = *(const uint4*)(pooled + (size_t)s2 * F + cg * 8);
        uint4 v3 = *(const uint4*)(pooled + (size_t)s3 * F + cg * 8);
        m0 = pk_max_u16(m0, pk_max_u16(pk_max_u16(v0.x, v1.x), pk_max_u16(v2.x, v3.x)));
        m1 = pk_max_u16(m1, pk_max_u16(pk_max_u16(v0.y, v1.y), pk_max_u16(v2.y, v3.y)));
        m2 = pk_max_u16(m2, pk_max_u16(pk_max_u16(v0.z, v1.z), pk_max_u16(v2.z, v3.z)));
        m3 = pk_max_u16(m3, pk_max_u16(pk_max_u16(v0.w, v1.w), pk_max_u16(v2.w, v3.w)));
    }
    for (; j < end; ++j) {
        int s = srcs[j];
        uint4 v = *(const uint4*)(pooled + (size_t)s * F + cg * 8);
        m0 = pk_max_u16(m0, v.x);
        m1 = pk_max_u16(m1, v.y);
        m2 = pk_max_u16(m2, v.z);
        m3 = pk_max_u16(m3, v.w);
    }
    uint4 o; o.x = m0; o.y = m1; o.z = m2; o.w = m3;
    *(uint4*)(agg + (size_t)n * F + cg * 8) = o;
}

__global__ __launch_bounds__(64)
void fake_k(const unsigned short* __restrict__ mirna, const float* __restrict__ noise,
            const int* __restrict__ t_p, const int* __restrict__ left_p,
            unsigned short* __restrict__ adj_s, float* __restrict__ fake_out)
{
    int r = blockIdx.x, c = threadIdx.x;
    int t = *t_p, left = *left_p;
    int row = left + r;
    float x = bits2f(mirna[(size_t)row * 64 + c]);
    float s = fabsf(x);
#pragma unroll
    for (int off = 32; off > 0; off >>= 1) s += __shfl_down(s, off);
    s = __shfl(s, 0);
    float ab = 1.f;
    for (int i = 0; i <= t; ++i)
        ab *= (1.f - (1e-4f + (0.02f - 1e-4f) * ((float)i / 99.f)));
    float v = sqrtf(ab) * (x / fmaxf(s, 1e-12f)) + sqrtf(1.f - ab) * noise[(size_t)row * 64 + c];
    adj_s[(size_t)r * 4160 + 4096 + c] = f2bits(v);   // fake tail of strided Adj
    fake_out[(size_t)r * 64 + c] = v;
}

// ---------------------------------------------------------------------------
extern "C" void kernel_launch(void* const* d_in, const int* in_sizes, int n_in,
                              void* d_out, int out_size, void* d_ws, size_t ws_size,
                              hipStream_t stream)
{
    const float* h0[3]    = {(const float*)d_in[0], (const float*)d_in[1], (const float*)d_in[2]};
    const float* Wpool[3] = {(const float*)d_in[3], (const float*)d_in[8],  (const float*)d_in[13]};
    const float* bpool[3] = {(const float*)d_in[4], (const float*)d_in[9],  (const float*)d_in[14]};
    const float* bself[3] = {(const float*)d_in[6], (const float*)d_in[11], (const float*)d_in[16]};
    const float* Wself[3] = {(const float*)d_in[5], (const float*)d_in[10], (const float*)d_in[15]};
    const float* Wneigh[3]= {(const float*)d_in[7], (const float*)d_in[12], (const float*)d_in[17]};
    const float* Adj   = (const float*)d_in[18];
    const float* noise = (const float*)d_in[19];
    const float* W1 = (const float*)d_in[20]; const float* b1 = (const float*)d_in[21];
    const float* W2 = (const float*)d_in[22]; const float* b2 = (const float*)d_in[23];
    const float* W3 = (const float*)d_in[24]; const float* b3 = (const float*)d_in[25];
    const float* W4 = (const float*)d_in[26]; const float* b4 = (const float*)d_in[27];
    const int* edges  = (const int*)d_in[28];
    const int* t_p    = (const int*)d_in[29];
    const int* left_p = (const int*)d_in[31];

    // workspace layout (bf16-element offsets)
    unsigned short* ws = (unsigned short*)d_ws;
    const size_t P1 = 0, P2 = 98304, P3 = 122880;
    const size_t FU1 = 147456, FU2 = 245760, FU3 = 294912;   // fused pair weights
    const size_t W1T = 344064, W2T = 1409024, W3T = 1540096, W4T = 2064384;
    const size_t ADJ = 6258688;        // 4096*4160 bf16 (strided, fake tail)
    const size_t POOLED = 23298048;    // 25.6MB region (to HA)
    const size_t HA = 36098048, HB = 45698048;   // 3*50000*64 bf16 each
    int* bcur  = (int*)(ws + 55298048);          // 6*NBKT
    int* bbase = bcur + 6 * NBKT;                // 6*NBKT
    int* offs  = bbase + 6 * NBKT;               // 6*(NNODE+1)
    unsigned short* srcs = (unsigned short*)(offs + 6 * (NNODE + 1)); // 6*NEDGE u16
    unsigned* ebuf = (unsigned*)(ws + POOLED);   // 6*RELEB u32 (15.7MB); dead before layer 1
    unsigned short* x1 = ws + POOLED;            // MLP scratch (dead after layer 3)
    unsigned short* x2 = x1 + (size_t)SZ * 256;
    unsigned short* x3 = x2 + (size_t)SZ * 512;
    unsigned short* adj_s = ws + ADJ;
    float* out_fake = (float*)d_out;
    float* out_x    = out_fake + (size_t)SZ * 64;
    // out_x (64MB) as scratch until fake_k:
    unsigned short* hb0 = (unsigned short*)out_x;     // h0 bf16 (38.4MB), layer 1
    unsigned short* agg2_l1 = hb0 + 19200000;         // layer-1 agg2 (25.6MB tail)
    unsigned short* pooled6 = (unsigned short*)out_x; // layers 2/3 pooled (38.4MB)
    unsigned short* aggB6 = pooled6 + 19200000;       // agg slots 4-5 (12.8MB)
    unsigned short* aggA6 = ws + POOLED;              // agg slots 0-3 (25.6MB)
    float* x1p = out_x;                               // MLP1 partials (ZK1*4MB)

    const int SRCr[6] = {0, 1, 0, 2, 2, 1};
    const int PAe[3] = {1, 0, 2}, PBe[3] = {3, 4, 5};   // dst pairs: p -> (eA,eB), dst=p
    dim3 T(256);

    // ---- prep: weight transposes (merged) + conversions ----
    transpose_cvt<<<dim3(4, 4, 6), T, 0, stream>>>(Wpool[0], nullptr, ws + P1, 128, 0, 128,
                                                   nullptr, nullptr);
    transpose_cvt<<<dim3(2, 2, 12), T, 0, stream>>>(Wpool[1], nullptr, ws + P2, 64, 0, 64,
                                                    Wpool[2], ws + P3);
    fuse_w_k<<<dim3(4, 2, 3), T, 0, stream>>>(Wself[0], Wneigh[0], ws + FU1, 128,
                                              nullptr, nullptr, nullptr);
    fuse_w_k<<<dim3(2, 2, 6), T, 0, stream>>>(Wself[1], Wneigh[1], ws + FU2, 64,
                                              Wself[2], Wneigh[2], ws + FU3);
    transpose_cvt<<<dim3(130, 8, 1), T, 0, stream>>>(W1, nullptr, ws + W1T, 4160, 0, 256,
                                                     nullptr, nullptr);
    tcvt_mlp_k<<<dim3(32, 128, 3), T, 0, stream>>>(W2, W3, W4, ws + W2T, ws + W3T, ws + W4T);
    cvt_adj_k<<<16384, T, 0, stream>>>(Adj, adj_s);
    cvt3_k<<<dim3(6250, 1, 3), T, 0, stream>>>(h0[0], h0[1], h0[2], hb0);

    // ---- CSR build ----
    binit_k<<<6, T, 0, stream>>>(bcur);
    bucket_k<<<dim3(123, 6), T, 0, stream>>>(edges, bcur, ebuf);
    bscan_k<<<6, T, 0, stream>>>(bcur, bbase, offs);
    debucket_k<<<dim3(NBKT, 6), T, 0, stream>>>(ebuf, bcur, bbase, offs, srcs);

    // ---- layer 1 (hb0 bf16, 128 -> 64), z=2-batched per dst pair ----
    for (int p = 0; p < 3; ++p) {
        const int eA = PAe[p], eB = PBe[p];
        pool2_k<8><<<dim3(1, 782, 2), T, 0, stream>>>(
            hb0 + (size_t)SRCr[eA] * NNODE * 128, hb0 + (size_t)SRCr[eB] * NNODE * 128,
            ws + P1 + (size_t)eA * 16384, ws + P1 + (size_t)eB * 16384,
            bpool[0] + eA * 128, bpool[0] + eB * 128,
            ws + POOLED, NNODE, 128);
        gather2_k<128><<<dim3(3125, 1, 2), T, 0, stream>>>(
            ws + POOLED, offs, srcs, agg2_l1, eA, eB);
        mfma_gemm<4><<<dim3(1, 782), T, 0, stream>>>(
            hb0 + (size_t)p * NNODE * 128, agg2_l1, agg2_l1 + (size_t)NNODE * 128,
            ws + FU1 + (size_t)p * 24576, bself[0] + eA * 64, bself[0] + eB * 64,
            ws + HA + (size_t)p * NNODE * 64, NNODE, 64, 128, 128, 128);
    }

    // ---- layers 2,3 (bf16, 64 -> 64), fully z-batched: 3 dispatches/layer ----
    unsigned short* hin = ws + HA;
    unsigned short* hout = ws + HB;
    for (int layer = 1; layer <= 2; ++layer) {
        const unsigned short* pT = ws + (layer == 1 ? P2 : P3);
        const unsigned short* fT = ws + (layer == 1 ? FU2 : FU3);
        pool6_k<<<dim3(1, 782, 6), T, 0, stream>>>(hin, pT, bpool[layer], pooled6, NNODE);
        gather6_k<<<dim3(1563, 1, 6), T, 0, stream>>>(pooled6, offs, srcs, aggA6, aggB6);
        fused3_k<<<dim3(1, 782, 3), T, 0, stream>>>(hin, aggA6, aggB6, fT,
                                                    bself[layer], hout, NNODE);
        unsigned short* tmp = hin; hin = hout; hout = tmp;
    }
    // hin == ws+HA holds h3; out_x region dead from here

    fake_k<<<SZ, dim3(64), 0, stream>>>(hin, noise, t_p, left_p, adj_s, out_fake);

    // ---- MLP: PIPE=1 (dbuf) for grid-starved layers, PIPE=0 for MLP4 ----
    gemm128<0, 0, 0, 1, 1><<<dim3(2, 32, ZK1), T, 0, stream>>>(
        adj_s, ws + W1T, b1, x1p, SZ, 256, 4160);
    mlp1_ep_k<<<1024, T, 0, stream>>>(x1p, b1, x1);
    gemm128<1, 0, 0, 0, 1><<<dim3(4, 32),  T, 0, stream>>>(x1, ws + W2T, b2, x2, SZ, 512, 256);
    gemm128<1, 0, 0, 0, 1><<<dim3(8, 32),  T, 0, stream>>>(x2, ws + W3T, b3, x3, SZ, 1024, 512);
    // MLP4 split into two N-halves (visibility into the mid-tier; ~neutral perf)
    gemm128<0, 1, 1, 0, 0><<<dim3(16, 32), T, 0, stream>>>(
        x3, ws + W4T, b4, out_x, SZ, 4096, 1024);
    gemm128<0, 1, 1, 0, 0><<<dim3(16, 32), T, 0, stream>>>(
        x3, ws + W4T + (size_t)2048 * 1024, b4 + 2048, out_x + 2048, SZ, 4096, 1024);
}